// Round 14
// baseline (560.863 us; speedup 1.0000x reference)
//
#include <hip/hip_runtime.h>
#include <hip/hip_bf16.h>

#define DEV static __device__ __forceinline__

typedef float f32x4 __attribute__((ext_vector_type(4)));
typedef __bf16 b16x8 __attribute__((ext_vector_type(8)));

DEV unsigned short f2bf(float f) {
  union { __hip_bfloat16 h; unsigned short u; } cv;
  cv.h = __float2bfloat16(f);
  return cv.u;
}

DEV void gload_lds16(const unsigned short* g, unsigned short* l) {
  __builtin_amdgcn_global_load_lds(
      (__attribute__((address_space(1))) void*)g,
      (__attribute__((address_space(3))) void*)l, 16, 0, 0);
}

// ---------------- all f32->bf16 conversions in ONE launch (6 tensors) --------
__global__ __launch_bounds__(256) void k_convall(
    const float* __restrict__ in1, const float* __restrict__ in2,
    const float* __restrict__ in3, const float* __restrict__ Wq,
    const float* __restrict__ Wk, const float* __restrict__ Wv,
    unsigned short* __restrict__ in1b, unsigned short* __restrict__ in2b,
    unsigned short* __restrict__ in3b, unsigned short* __restrict__ wqb,
    unsigned short* __restrict__ wkb, unsigned short* __restrict__ wvb) {
  const int b = blockIdx.x;
  const float* src;
  unsigned short* dst;
  long long off;
  if (b < 4096) { src = in1; dst = in1b; off = b; }
  else if (b < 8192) { src = in2; dst = in2b; off = b - 4096; }
  else if (b < 12288) { src = in3; dst = in3b; off = b - 8192; }
  else if (b < 14336) { src = Wq; dst = wqb; off = b - 12288; }
  else if (b < 16384) { src = Wk; dst = wkb; off = b - 14336; }
  else { src = Wv; dst = wvb; off = b - 16384; }
  const long long i = off * 256 + threadIdx.x;
  const float4 v = ((const float4*)src)[i];
  ushort4 o;
  o.x = f2bf(v.x); o.y = f2bf(v.y); o.z = f2bf(v.z); o.w = f2bf(v.w);
  ((ushort4*)dst)[i] = o;
}

// ---------------- f32 [z][R][C] -> bf16 [z][C][R] ----------------
__global__ __launch_bounds__(256) void k_transpose_bf16(const float* __restrict__ src,
                                                        unsigned short* __restrict__ dst,
                                                        int R, int C) {
  __shared__ float t[32][33];
  const long long zo = (long long)blockIdx.z * R * C;
  const int c0 = blockIdx.x * 32, r0 = blockIdx.y * 32;
  const int tx = threadIdx.x & 31, ty = threadIdx.x >> 5;
#pragma unroll
  for (int i = 0; i < 4; ++i)
    t[ty + i * 8][tx] = src[zo + (long long)(r0 + ty + i * 8) * C + c0 + tx];
  __syncthreads();
#pragma unroll
  for (int i = 0; i < 4; ++i)
    dst[zo + (long long)(c0 + ty + i * 8) * R + r0 + tx] = f2bf(t[tx][ty + i * 8]);
}

// ---------------- u[h,d]=sum_e Wq[h,d,e]*bk[h,e] (sel0) / v from Wk,bq (sel1) ----------------
__global__ __launch_bounds__(256) void k_uv(const float* __restrict__ Wq, const float* __restrict__ bk,
                                            const float* __restrict__ Wk, const float* __restrict__ bq,
                                            float* __restrict__ u, float* __restrict__ v) {
  const int sel = blockIdx.y;
  const float* W = sel ? Wk : Wq;
  const float* bb = sel ? bq : bk;
  float* dst = sel ? v : u;
  const int wave = threadIdx.x >> 6, lane = threadIdx.x & 63;
  const int idx = blockIdx.x * 4 + wave;
  const int h = idx >> 9, d = idx & 511;
  const float* wr = W + ((long long)h * 512 + d) * 512 + lane * 8;
  const float* br = bb + h * 512 + lane * 8;
  float s = 0.f;
#pragma unroll
  for (int k = 0; k < 8; ++k) s += wr[k] * br[k];
#pragma unroll
  for (int off = 32; off; off >>= 1) s += __shfl_xor(s, off);
  if (lane == 0) dst[h * 512 + d] = s;
}

// ---------------- c[h] = bq[h].bk[h] ----------------
__global__ __launch_bounds__(512) void k_bdot(const float* __restrict__ bq,
                                              const float* __restrict__ bk,
                                              float* __restrict__ c) {
  const int wave = threadIdx.x >> 6, lane = threadIdx.x & 63;
  const float* a = bq + wave * 512 + lane * 8;
  const float* b = bk + wave * 512 + lane * 8;
  float s = 0.f;
#pragma unroll
  for (int k = 0; k < 8; ++k) s += a[k] * b[k];
#pragma unroll
  for (int off = 32; off; off >>= 1) s += __shfl_xor(s, off);
  if (lane == 0) c[wave] = s;
}

// ---------------- rt[b*8+h][i] = in1[b,i,:].u[h,:] + c[h]; ct from in2,v ----------------
__global__ __launch_bounds__(256) void k_rtct(const float* __restrict__ in1, const float* __restrict__ in2,
                                              const float* __restrict__ u, const float* __restrict__ v,
                                              const float* __restrict__ cbuf,
                                              float* __restrict__ rt, float* __restrict__ ct) {
  const int sel = blockIdx.y;
  const float* src = sel ? in2 : in1;
  const float* vec = sel ? v : u;
  float* dst = sel ? ct : rt;
  const int row = blockIdx.x;
  __shared__ float x[512];
  const float* p = src + (long long)row * 512;
  x[threadIdx.x] = p[threadIdx.x];
  x[threadIdx.x + 256] = p[threadIdx.x + 256];
  __syncthreads();
  const int wave = threadIdx.x >> 6, lane = threadIdx.x & 63;
  const int b = row >> 10, i = row & 1023;
#pragma unroll
  for (int t = 0; t < 2; ++t) {
    const int h = wave * 2 + t;
    const float* wv = vec + h * 512;
    float s = 0.f;
#pragma unroll
    for (int k = 0; k < 8; ++k) s += x[lane + k * 64] * wv[lane + k * 64];
#pragma unroll
    for (int off = 32; off; off >>= 1) s += __shfl_xor(s, off);
    if (lane == 0)
      dst[((long long)(b * 8 + h)) * 1024 + i] = s + (sel ? 0.f : cbuf[h]);
  }
}

// ---------------- bvo[h][e'] = sum_e bv[h][e] * Wo[h*512+e][e'] ----------------
__global__ __launch_bounds__(256) void k_bvo(const float* __restrict__ Wo,
                                             const float* __restrict__ bv,
                                             float* __restrict__ bvo) {
  const int h = blockIdx.x;
  __shared__ float bs[512];
  bs[threadIdx.x] = bv[h * 512 + threadIdx.x];
  bs[threadIdx.x + 256] = bv[h * 512 + threadIdx.x + 256];
  __syncthreads();
  float a0 = 0.f, a1 = 0.f;
  for (int e = 0; e < 512; ++e) {
    const float* row = Wo + ((long long)(h * 512 + e)) * 512;
    a0 += bs[e] * row[threadIdx.x];
    a1 += bs[e] * row[threadIdx.x + 256];
  }
  bvo[h * 512 + threadIdx.x] = a0;
  bvo[h * 512 + threadIdx.x + 256] = a1;
}

// ---------------- old 128x128 GEMM (small weight-product GEMMs) ----------------
template <int OM>
__global__ __launch_bounds__(256) void k_gemm_bt(
    const unsigned short* __restrict__ A, const unsigned short* __restrict__ Bt,
    void* __restrict__ Cv, const float* __restrict__ bias,
    const float* __restrict__ rAdd, const float* __restrict__ cAdd,
    int K, int lda, int ldb, int ldc,
    int azs, int azm, long long azr,
    int bzs, int bzm, long long bzr,
    int czs, long long czr, int czm, int czc,
    int biasm, int bstr, int rstr, float scale) {
  __shared__ unsigned short lA[128 * 64];
  __shared__ unsigned short lB[128 * 64];
  const int tid = threadIdx.x, wave = tid >> 6, lane = tid & 63;
  const int z = blockIdx.z;
  const int m0 = blockIdx.y * 128, n0 = blockIdx.x * 128;
  const unsigned short* Az = A + (long long)((z >> azs) & azm) * azr + (long long)m0 * lda;
  const unsigned short* Bz = Bt + (long long)((z >> bzs) & bzm) * bzr + (long long)n0 * ldb;

  const int srow = wave * 32 + (lane >> 3);
  const int scol = (lane & 7) * 8;
  const unsigned short* ga = Az + (long long)srow * lda + scol;
  const unsigned short* gb = Bz + (long long)srow * ldb + scol;
  unsigned short* laBase = &lA[(wave * 32) * 64];
  unsigned short* lbBase = &lB[(wave * 32) * 64];

  f32x4 acc[4][4] = {};
  const int wr = (wave >> 1) * 64, wc = (wave & 1) * 64;
  const int fr = lane & 15, kq = (lane >> 4) * 8;

  for (int k0 = 0; k0 < K; k0 += 64) {
#pragma unroll
    for (int i = 0; i < 4; ++i) {
      gload_lds16(ga + (long long)(i * 8) * lda + k0, laBase + (i * 8) * 64);
      gload_lds16(gb + (long long)(i * 8) * ldb + k0, lbBase + (i * 8) * 64);
    }
    __syncthreads();
#pragma unroll
    for (int kk = 0; kk < 64; kk += 32) {
      b16x8 af[4], bf[4];
#pragma unroll
      for (int i = 0; i < 4; ++i)
        af[i] = *(const b16x8*)&lA[(wr + i * 16 + fr) * 64 + kk + kq];
#pragma unroll
      for (int j = 0; j < 4; ++j)
        bf[j] = *(const b16x8*)&lB[(wc + j * 16 + fr) * 64 + kk + kq];
#pragma unroll
      for (int i = 0; i < 4; ++i)
#pragma unroll
        for (int j = 0; j < 4; ++j)
          acc[i][j] = __builtin_amdgcn_mfma_f32_16x16x32_bf16(af[i], bf[j], acc[i][j], 0, 0, 0);
    }
    __syncthreads();
  }

  const long long coff = (long long)(z >> czs) * czr + (long long)(z & czm) * czc;
  const long long zr = (long long)z * rstr;
  const int rr = (lane >> 4) * 4;
#pragma unroll
  for (int j = 0; j < 4; ++j) {
    const int col = n0 + wc + j * 16 + fr;
    const float bval = bias ? bias[(long long)(z & biasm) * bstr + col] : 0.f;
    const float ca = cAdd ? cAdd[zr + col] : 0.f;
#pragma unroll
    for (int i = 0; i < 4; ++i) {
#pragma unroll
      for (int r = 0; r < 4; ++r) {
        const int row = m0 + wr + i * 16 + rr + r;
        const float ra = rAdd ? rAdd[zr + row] : 0.f;
        const float val = (acc[i][j][r] + ra + ca) * scale + bval;
        if constexpr (OM == 1) {
          ((unsigned short*)Cv)[coff + (long long)row * ldc + col] = f2bf(val);
        } else if constexpr (OM == 2) {
          ((unsigned short*)Cv)[coff + (long long)col * ldc + row] = f2bf(val);
        } else {
          ((float*)Cv)[coff + (long long)row * ldc + col] = val;
        }
      }
    }
  }
}

// ================= 256x256 stage-early GEMM; ES=1 adds exp + row-sum atomics =
#define STAGE_A8(nb, koff, i)                                  \
  gload_lds16(gaL + (long long)((i) * 8) * lda + (koff) + scol, \
              &sh[nb][(wid * 32 + (i) * 8) * 64])
#define STAGE_B8(nb, koff, i)                                  \
  gload_lds16(gbL + (long long)((i) * 8) * ldb + (koff) + scol, \
              &sh[2 + (nb)][(wid * 32 + (i) * 8) * 64])

template <int OM, int ES>
__global__ __launch_bounds__(512, 2) void k_gemm8p(
    const unsigned short* __restrict__ A, const unsigned short* __restrict__ Bt,
    void* __restrict__ Cv, const float* __restrict__ bias,
    const float* __restrict__ rAdd, const float* __restrict__ cAdd,
    float* __restrict__ rsum,
    int K, int lda, int ldb, int ldc,
    int azs, int azm, long long azr,
    int bzs, int bzm, long long bzr,
    int czs, long long czr, int czm, int czc,
    int biasm, int bstr, int rstr, float scale, int kzm, int kzr) {
  __shared__ unsigned short sh[4][256 * 64];
  const int tid = threadIdx.x, wid = tid >> 6, lane = tid & 63;
  const int wm = wid >> 2, wn = wid & 3;

  const int gx = gridDim.x, gy = gridDim.y;
  const int nwg = gx * gy * gridDim.z;
  const int bidL = blockIdx.x + gx * (blockIdx.y + gy * blockIdx.z);
  const int q8 = nwg >> 3;
  const int idx = (bidL & 7) * q8 + (bidL >> 3);
  const int bx = idx % gx;
  const int rem = idx / gx;
  const int by = rem % gy;
  const int z = rem / gy;

  const int m0 = by * 256, n0 = bx * 256;
  const int kstart = (z & kzm) * kzr;
  const unsigned short* Az = A + (long long)((z >> azs) & azm) * azr + (long long)m0 * lda + kstart;
  const unsigned short* Bz = Bt + (long long)((z >> bzs) & bzm) * bzr + (long long)n0 * ldb + kstart;

  const int scol = (((lane & 7) ^ ((lane >> 3) & 7)) << 3);
  const unsigned short* gaL = Az + (long long)(wid * 32 + (lane >> 3)) * lda;
  const unsigned short* gbL = Bz + (long long)(wid * 32 + (lane >> 3)) * ldb;

  const int fr = lane & 15, kq = (lane >> 4) * 8;
  const int fsw = (fr & 7) << 3;
  const int rc0 = kq ^ fsw;
  const int rc1 = (32 + kq) ^ fsw;
  const int aBase = (wm * 128 + fr) * 64;
  const int bBase = (wn * 64 + fr) * 64;

  f32x4 acc[8][4] = {};
  b16x8 afr[4][2], bfr[4][2];
  const int NT = K >> 6;

#pragma unroll
  for (int i = 0; i < 4; ++i) { STAGE_A8(0, 0, i); STAGE_B8(0, 0, i); }

  for (int kt = 0; kt < NT; ++kt) {
    const int cur = kt & 1, nb = cur ^ 1;
    if (kt + 1 < NT) {
      const int ko = (kt + 1) << 6;
#pragma unroll
      for (int i = 0; i < 4; ++i) { STAGE_A8(nb, ko, i); STAGE_B8(nb, ko, i); }
      asm volatile("s_waitcnt vmcnt(8)" ::: "memory");
    } else {
      asm volatile("s_waitcnt vmcnt(0)" ::: "memory");
    }
    __builtin_amdgcn_s_barrier();
    __builtin_amdgcn_sched_barrier(0);

#pragma unroll
    for (int i = 0; i < 4; ++i) {
      afr[i][0] = *(const b16x8*)&sh[cur][aBase + i * 1024 + rc0];
      afr[i][1] = *(const b16x8*)&sh[cur][aBase + i * 1024 + rc1];
    }
#pragma unroll
    for (int j = 0; j < 2; ++j) {
      bfr[j][0] = *(const b16x8*)&sh[2 + cur][bBase + j * 1024 + rc0];
      bfr[j][1] = *(const b16x8*)&sh[2 + cur][bBase + j * 1024 + rc1];
    }
    __builtin_amdgcn_s_setprio(1);
#pragma unroll
    for (int t = 0; t < 2; ++t)
#pragma unroll
      for (int i = 0; i < 4; ++i)
#pragma unroll
        for (int j = 0; j < 2; ++j)
          acc[i][j] = __builtin_amdgcn_mfma_f32_16x16x32_bf16(afr[i][t], bfr[j][t], acc[i][j], 0, 0, 0);
    __builtin_amdgcn_s_setprio(0);
#pragma unroll
    for (int j = 2; j < 4; ++j) {
      bfr[j][0] = *(const b16x8*)&sh[2 + cur][bBase + j * 1024 + rc0];
      bfr[j][1] = *(const b16x8*)&sh[2 + cur][bBase + j * 1024 + rc1];
    }
    __builtin_amdgcn_s_setprio(1);
#pragma unroll
    for (int t = 0; t < 2; ++t)
#pragma unroll
      for (int i = 0; i < 4; ++i)
#pragma unroll
        for (int j = 2; j < 4; ++j)
          acc[i][j] = __builtin_amdgcn_mfma_f32_16x16x32_bf16(afr[i][t], bfr[j][t], acc[i][j], 0, 0, 0);
    __builtin_amdgcn_s_setprio(0);
#pragma unroll
    for (int i = 0; i < 4; ++i) {
      afr[i][0] = *(const b16x8*)&sh[cur][aBase + (i + 4) * 1024 + rc0];
      afr[i][1] = *(const b16x8*)&sh[cur][aBase + (i + 4) * 1024 + rc1];
    }
    __builtin_amdgcn_s_setprio(1);
#pragma unroll
    for (int t = 0; t < 2; ++t)
#pragma unroll
      for (int i = 0; i < 4; ++i)
#pragma unroll
        for (int j = 0; j < 2; ++j)
          acc[i + 4][j] = __builtin_amdgcn_mfma_f32_16x16x32_bf16(afr[i][t], bfr[j][t], acc[i + 4][j], 0, 0, 0);
    __builtin_amdgcn_s_setprio(0);
    __builtin_amdgcn_s_setprio(1);
#pragma unroll
    for (int t = 0; t < 2; ++t)
#pragma unroll
      for (int i = 0; i < 4; ++i)
#pragma unroll
        for (int j = 2; j < 4; ++j)
          acc[i + 4][j] = __builtin_amdgcn_mfma_f32_16x16x32_bf16(afr[i][t], bfr[j][t], acc[i + 4][j], 0, 0, 0);
    __builtin_amdgcn_s_setprio(0);

    __builtin_amdgcn_s_barrier();
  }

  const long long coff = (long long)(z >> czs) * czr + (long long)(z & czm) * czc;
  const long long zr = (long long)z * rstr;
  const int rr = (lane >> 4) * 4;
  unsigned short* flat = &sh[0][0];

  float rp[8][4];
  if constexpr (ES) {
#pragma unroll
    for (int i = 0; i < 8; ++i)
#pragma unroll
      for (int r = 0; r < 4; ++r) rp[i][r] = 0.f;
  }

#pragma unroll
  for (int j = 0; j < 4; ++j) {
    const int col = n0 + wn * 64 + j * 16 + fr;
    const float bval = bias ? bias[(long long)(z & biasm) * bstr + col] : 0.f;
    const float ca = cAdd ? cAdd[zr + col] : 0.f;
#pragma unroll
    for (int i = 0; i < 8; ++i) {
#pragma unroll
      for (int r = 0; r < 4; ++r) {
        const int row = m0 + wm * 128 + i * 16 + rr + r;
        const float ra = rAdd ? rAdd[zr + row] : 0.f;
        float val = (acc[i][j][r] + ra + ca) * scale + bval;
        if constexpr (ES) {
          val = __expf(val);  // scores bounded (|s|<~1): max-sub not needed
          rp[i][r] += val;
        }
        const int rowL = wm * 128 + i * 16 + rr + r;
        const int colL = wn * 64 + j * 16 + fr;
        const int sR = (OM == 2) ? colL : rowL;
        const int sC = (OM == 2) ? rowL : colL;
        flat[sR * 256 + (sC ^ ((sR & 7) << 3))] = f2bf(val);
      }
    }
  }
  if constexpr (ES) {
#pragma unroll
    for (int i = 0; i < 8; ++i)
#pragma unroll
      for (int r = 0; r < 4; ++r) {
        float v = rp[i][r];
        v += __shfl_xor(v, 1); v += __shfl_xor(v, 2);
        v += __shfl_xor(v, 4); v += __shfl_xor(v, 8);
        if (fr == 0) {
          const int rowL = wm * 128 + i * 16 + rr + r;
          const long long ridx =
              ((long long)(z >> 3) * 1024 + m0 + rowL) * 8 + (z & 7);
          atomicAdd(&rsum[ridx], v);
        }
      }
  }
  __builtin_amdgcn_s_barrier();
  const long long rbase = (OM == 2) ? (long long)n0 : (long long)m0;
  const long long cbase = (OM == 2) ? (long long)m0 : (long long)n0;
  unsigned short* Cb = (unsigned short*)Cv;
#pragma unroll
  for (int it = 0; it < 16; ++it) {
    const int t = it * 512 + tid;
    const int R = t >> 5;
    const int Cq = t & 31;
    const int q = Cq ^ (R & 7);
    const b16x8 v = *(const b16x8*)&flat[R * 256 + q * 8];
    *(b16x8*)(Cb + coff + (rbase + R) * ldc + cbase + Cq * 8) = v;
  }
}

// ===== 128x128 stage-early GEMM; SEG=1: per-h-segment softmax normalization ==
#define STAGE_GA(nb, koff, i)                                  \
  gload_lds16(gaL + (long long)((i) * 8) * lda + (koff) + scol, \
              &sh[nb][(wid * 32 + (i) * 8) * 64])
#define STAGE_GB(nb, koff, i)                                  \
  gload_lds16(gbL + (long long)((i) * 8) * ldb + (koff) + scol, \
              &sh[2 + (nb)][(wid * 32 + (i) * 8) * 64])

template <int OM, int SEG>
__global__ __launch_bounds__(256, 2) void k_g128(
    const unsigned short* __restrict__ A, const unsigned short* __restrict__ Bt,
    void* __restrict__ Cv, const float* __restrict__ bias,
    const float* __restrict__ rsum,
    int K, int lda, int ldb, int ldc,
    int azs, int azm, long long azr,
    int bzs, int bzm, long long bzr,
    int czs, long long czr, int czm, int czc,
    int biasm, int bstr, float scale, int kzm, int kzr) {
  __shared__ unsigned short sh[4][128 * 64];
  __shared__ float rsl[1024];
  const int tid = threadIdx.x, wid = tid >> 6, lane = tid & 63;
  const int wm = wid >> 1, wn = wid & 1;

  const int gx = gridDim.x, gy = gridDim.y;
  const int nwg = gx * gy * gridDim.z;
  const int bidL = blockIdx.x + gx * (blockIdx.y + gy * blockIdx.z);
  const int q8 = nwg >> 3;
  const int idx = (bidL & 7) * q8 + (bidL >> 3);
  const int bx = idx % gx;
  const int rem = idx / gx;
  const int by = rem % gy;
  const int z = rem / gy;

  const int m0 = by * 128, n0 = bx * 128;
  const int kstart = (z & kzm) * kzr;
  const unsigned short* Az = A + (long long)((z >> azs) & azm) * azr + (long long)m0 * lda + kstart;
  const unsigned short* Bz = Bt + (long long)((z >> bzs) & bzm) * bzr + (long long)n0 * ldb + kstart;

  const int scol = (((lane & 7) ^ ((lane >> 3) & 7)) << 3);
  const unsigned short* gaL = Az + (long long)(wid * 32 + (lane >> 3)) * lda;
  const unsigned short* gbL = Bz + (long long)(wid * 32 + (lane >> 3)) * ldb;

  const int fr = lane & 15, kq = (lane >> 4) * 8;
  const int fsw = (fr & 7) << 3;
  const int rc0 = kq ^ fsw;
  const int rc1 = (32 + kq) ^ fsw;
  const int aBase = (wm * 64 + fr) * 64;
  const int bBase = (wn * 64 + fr) * 64;
  const int rr = (lane >> 4) * 4;

  if constexpr (SEG) {
#pragma unroll
    for (int qq = 0; qq < 4; ++qq) {
      const int tt = tid * 4 + qq;
      const int row = tt >> 3, hh = tt & 7;
      rsl[tt] = 1.0f / rsum[((long long)z * 1024 + m0 + row) * 8 + hh];
    }
  }

  f32x4 acc[4][4] = {};
  f32x4 accH[4][4] = {};
  b16x8 afr[4][2], bfr[4][2];
  const int NT = K >> 6;

#pragma unroll
  for (int i = 0; i < 4; ++i) { STAGE_GA(0, 0, i); STAGE_GB(0, 0, i); }

  for (int kt = 0; kt < NT; ++kt) {
    const int cur = kt & 1, nb = cur ^ 1;
    if (kt + 1 < NT) {
      const int ko = (kt + 1) << 6;
#pragma unroll
      for (int i = 0; i < 4; ++i) { STAGE_GA(nb, ko, i); STAGE_GB(nb, ko, i); }
      asm volatile("s_waitcnt vmcnt(8)" ::: "memory");
    } else {
      asm volatile("s_waitcnt vmcnt(0)" ::: "memory");
    }
    __builtin_amdgcn_s_barrier();
    __builtin_amdgcn_sched_barrier(0);

#pragma unroll
    for (int i = 0; i < 4; ++i) {
      afr[i][0] = *(const b16x8*)&sh[cur][aBase + i * 1024 + rc0];
      afr[i][1] = *(const b16x8*)&sh[cur][aBase + i * 1024 + rc1];
    }
#pragma unroll
    for (int j = 0; j < 4; ++j) {
      bfr[j][0] = *(const b16x8*)&sh[2 + cur][bBase + j * 1024 + rc0];
      bfr[j][1] = *(const b16x8*)&sh[2 + cur][bBase + j * 1024 + rc1];
    }
#pragma unroll
    for (int t = 0; t < 2; ++t)
#pragma unroll
      for (int i = 0; i < 4; ++i)
#pragma unroll
        for (int j = 0; j < 4; ++j) {
          if constexpr (SEG)
            accH[i][j] = __builtin_amdgcn_mfma_f32_16x16x32_bf16(afr[i][t], bfr[j][t], accH[i][j], 0, 0, 0);
          else
            acc[i][j] = __builtin_amdgcn_mfma_f32_16x16x32_bf16(afr[i][t], bfr[j][t], acc[i][j], 0, 0, 0);
        }

    if constexpr (SEG) {
      if ((kt & 15) == 15) {  // h-segment boundary: acc += accH * rsinv[row][h]
        const int hh = kt >> 4;
#pragma unroll
        for (int i = 0; i < 4; ++i) {
          float sv[4];
#pragma unroll
          for (int r = 0; r < 4; ++r)
            sv[r] = rsl[(wm * 64 + i * 16 + rr + r) * 8 + hh];
#pragma unroll
          for (int j = 0; j < 4; ++j)
#pragma unroll
            for (int r = 0; r < 4; ++r) {
              acc[i][j][r] += accH[i][j][r] * sv[r];
              accH[i][j][r] = 0.f;
            }
        }
      }
    }

    __builtin_amdgcn_s_barrier();
  }

  const long long coff = (long long)(z >> czs) * czr + (long long)(z & czm) * czc;
  unsigned short* flat = &sh[0][0];

  if constexpr (OM == 1 || OM == 2) {
#pragma unroll
    for (int j = 0; j < 4; ++j) {
      const int col = n0 + wn * 64 + j * 16 + fr;
      const float bval = bias ? bias[(long long)(z & biasm) * bstr + col] : 0.f;
#pragma unroll
      for (int i = 0; i < 4; ++i) {
#pragma unroll
        for (int r = 0; r < 4; ++r) {
          const float val = acc[i][j][r] * scale + bval;
          const int rowL = wm * 64 + i * 16 + rr + r;
          const int colL = wn * 64 + j * 16 + fr;
          const int sR = (OM == 2) ? colL : rowL;
          const int sC = (OM == 2) ? rowL : colL;
          flat[sR * 128 + (sC ^ ((sR & 7) << 3))] = f2bf(val);
        }
      }
    }
    __builtin_amdgcn_s_barrier();
    const long long rbase = (OM == 2) ? (long long)n0 : (long long)m0;
    const long long cbase = (OM == 2) ? (long long)m0 : (long long)n0;
    unsigned short* Cb = (unsigned short*)Cv;
#pragma unroll
    for (int it = 0; it < 8; ++it) {
      const int t = it * 256 + tid;
      const int R = t >> 4;
      const int Cq = t & 15;
      const int q = Cq ^ (R & 7);
      const b16x8 v = *(const b16x8*)&flat[R * 128 + q * 8];
      *(b16x8*)(Cb + coff + (rbase + R) * ldc + cbase + Cq * 8) = v;
    }
  } else {
    float* fflat = (float*)flat;
    float* Cf = (float*)Cv;
#pragma unroll
    for (int j = 0; j < 4; ++j) {
      const int col = n0 + wn * 64 + j * 16 + fr;
      const float bval = bias ? bias[(long long)(z & biasm) * bstr + col] : 0.f;
#pragma unroll
      for (int i = 0; i < 4; ++i) {
#pragma unroll
        for (int r = 0; r < 4; ++r) {
          const float val = acc[i][j][r] * scale + bval;
          const int Rl = wm * 64 + i * 16 + rr + r;
          const int Cl = wn * 64 + j * 16 + fr;
          fflat[Rl * 128 + (Cl ^ ((Rl & 7) << 2))] = val;
        }
      }
    }
    __builtin_amdgcn_s_barrier();
#pragma unroll
    for (int it = 0; it < 16; ++it) {
      const int t = it * 256 + tid;
      const int R = t >> 5;
      const int Cq = t & 31;
      const int q = Cq ^ (R & 7);
      const float4 v = *(const float4*)&fflat[R * 128 + q * 4];
      *(float4*)(Cf + coff + (long long)(m0 + R) * ldc + n0 + Cq * 4) = v;
    }
  }
}

extern "C" void kernel_launch(void* const* d_in, const int* in_sizes, int n_in,
                              void* d_out, int out_size, void* d_ws, size_t ws_size,
                              hipStream_t stream) {
  const float* in1 = (const float*)d_in[0];
  const float* in2 = (const float*)d_in[1];
  const float* in3 = (const float*)d_in[2];
  const float* Wq = (const float*)d_in[3];
  const float* bq = (const float*)d_in[4];
  const float* Wk = (const float*)d_in[5];
  const float* bk = (const float*)d_in[6];
  const float* Wv = (const float*)d_in[7];
  const float* bv = (const float*)d_in[8];
  const float* Wo = (const float*)d_in[9];
  const float* bo = (const float*)d_in[10];

  const long long MB = 1024 * 1024;
  typedef unsigned short us;
  unsigned char* w = (unsigned char*)d_ws;
  us* in2b = (us*)(w);                  // 8 MB
  us* Tbuf = (us*)(w + 8 * MB);         // 64 MB: T, then Ubuf (T dead after scores)
  us* Ubuf = (us*)(w + 8 * MB);
  us* Pcat = (us*)(w + 72 * MB);        // 128 MB: P_cat = exp(scores), unnormalized
  us* in1b = (us*)(w + 200 * MB);       // 8 MB; first 2 MB become rsum after T
  float* rsum = (float*)(w + 200 * MB); // [65536 rows][8 h] f32, 2 MB
  us* wqb = (us*)(w + 216 * MB);        // 4 MB; Wvot overwrites after Gt
  us* Wvot = (us*)(w + 216 * MB);
  us* wkb = (us*)(w + 220 * MB);        // 4 MB
  us* wvb = (us*)(w + 224 * MB);        // 4 MB
  us* wotb = (us*)(w + 228 * MB);       // 4 MB
  us* Gt = (us*)(w + 232 * MB);         // 4 MB
  float* rt = (float*)(w + 236 * MB);   // 256 KB
  float* ct = (float*)(w + 236 * MB + (256 << 10));
  float* ubuf = (float*)(w + 237 * MB);
  float* vbuf = (float*)(w + 237 * MB + (16 << 10));
  float* cbuf = (float*)(w + 237 * MB + (32 << 10));
  float* bvo = (float*)(w + 237 * MB + (48 << 10));
  if ((long long)ws_size < 238 * MB) return;

  const float iscale = 0.04419417382415922f;  // 1/sqrt(512)
  const long long SD = 1024 * 512;            // 524288

  // conversions (6 tensors, 1 launch) + Wo transpose
  k_convall<<<18432, 256, 0, stream>>>(in1, in2, in3, Wq, Wk, Wv,
                                       in1b, in2b, (us*)(w + 208 * MB), wqb, wkb, wvb);
  us* in3b = (us*)(w + 208 * MB);
  k_transpose_bf16<<<dim3(16, 128, 1), 256, 0, stream>>>(Wo, wotb, 4096, 512);

  // bias cross-terms for scores
  k_uv<<<dim3(1024, 2), 256, 0, stream>>>(Wq, bk, Wk, bq, ubuf, vbuf);
  k_bdot<<<1, 512, 0, stream>>>(bq, bk, cbuf);
  k_rtct<<<dim3(8192, 2), 256, 0, stream>>>(in1, in2, ubuf, vbuf, cbuf, rt, ct);

  // Gt[h] = Wk[h] Wq[h]^T
  k_gemm_bt<1><<<dim3(4, 4, 8), 256, 0, stream>>>(
      wkb, wqb, Gt, nullptr, nullptr, nullptr, 512, 512, 512, 512,
      0, 7, 262144LL, 0, 7, 262144LL, 0, 262144LL, 0, 0, 0, 0, 0, 1.f);

  // Wvot[h][e'][d] = (Wv_h Wo_h)^T  (overwrites wqb; Gt already done)
  k_gemm_bt<1><<<dim3(4, 4, 8), 256, 0, stream>>>(
      wotb, wvb, Wvot, nullptr, nullptr, nullptr, 512, 4096, 512, 512,
      0, 7, 512LL, 0, 7, 262144LL, 0, 262144LL, 0, 0, 0, 0, 0, 1.f);
  // bvo[h] = bv[h] @ Wo_h
  k_bvo<<<8, 256, 0, stream>>>(Wo, bv, bvo);

  // T[z=b*8+h] = X1[b] G[h]   [64][1024][512] bf16
  k_gemm8p<1, 0><<<dim3(2, 4, 64), 512, 0, stream>>>(
      in1b, Gt, Tbuf, nullptr, nullptr, nullptr, nullptr, 512, 512, 512, 512,
      3, 7, SD, 0, 7, 262144LL, 0, SD, 0, 0, 0, 0, 0, 1.f, 0, 0);

  // zero rsum (in1b dead after T)
  hipMemsetAsync(rsum, 0, 2 * MB, stream);

  // scores -> P_cat = exp((T X2^T + rt + ct)*iscale); rsum accumulated
  k_gemm8p<1, 1><<<dim3(4, 4, 64), 512, 0, stream>>>(
      Tbuf, in2b, Pcat, nullptr, rt, ct, rsum, 512, 512, 512, 8192,
      0, 63, SD, 3, 7, SD, 3, 8388608LL, 7, 1024, 0, 0, 1024, iscale, 0, 0);

  // U_cat[b][e'][h*1024+s] = X3[b] Wvo_h + bvo_h  (overwrites Tbuf; T dead)
  k_gemm8p<2, 0><<<dim3(2, 4, 64), 512, 0, stream>>>(
      in3b, Wvot, Ubuf, bvo, nullptr, nullptr, nullptr, 512, 512, 512, 8192,
      3, 7, SD, 0, 7, 262144LL, 3, 4194304LL, 7, 1024, 7, 512, 0, 1.f, 0, 0);

  // out[b*1024+i][e'] = sum_h (Pe_h @ U_h^T)/rsum[row,h] + bo
  // M=8192,N=512,K=8192 (128 K-tiles, 8 h-segments), 256 blocks = 1/CU
  k_g128<0, 1><<<dim3(4, 8, 8), 256, 0, stream>>>(
      Pcat, Ubuf, d_out, bo, rsum, 8192, 8192, 8192, 512,
      0, 7, 8388608LL, 0, 7, 4194304LL, 0, 524288LL, 0, 0, 0, 0, 1.f, 0, 0);
}

// Round 16
// 484.737 us; speedup vs baseline: 1.1570x; 1.1570x over previous
//
#include <hip/hip_runtime.h>
#include <hip/hip_bf16.h>

#define DEV static __device__ __forceinline__

typedef float f32x4 __attribute__((ext_vector_type(4)));
typedef __bf16 b16x8 __attribute__((ext_vector_type(8)));

DEV unsigned short f2bf(float f) {
  union { __hip_bfloat16 h; unsigned short u; } cv;
  cv.h = __float2bfloat16(f);
  return cv.u;
}

DEV void gload_lds16(const unsigned short* g, unsigned short* l) {
  __builtin_amdgcn_global_load_lds(
      (__attribute__((address_space(1))) void*)g,
      (__attribute__((address_space(3))) void*)l, 16, 0, 0);
}

// ---------------- all f32->bf16 conversions in ONE launch (6 tensors) --------
__global__ __launch_bounds__(256) void k_convall(
    const float* __restrict__ in1, const float* __restrict__ in2,
    const float* __restrict__ in3, const float* __restrict__ Wq,
    const float* __restrict__ Wk, const float* __restrict__ Wv,
    unsigned short* __restrict__ in1b, unsigned short* __restrict__ in2b,
    unsigned short* __restrict__ in3b, unsigned short* __restrict__ wqb,
    unsigned short* __restrict__ wkb, unsigned short* __restrict__ wvb) {
  const int b = blockIdx.x;
  const float* src;
  unsigned short* dst;
  long long off;
  if (b < 4096) { src = in1; dst = in1b; off = b; }
  else if (b < 8192) { src = in2; dst = in2b; off = b - 4096; }
  else if (b < 12288) { src = in3; dst = in3b; off = b - 8192; }
  else if (b < 14336) { src = Wq; dst = wqb; off = b - 12288; }
  else if (b < 16384) { src = Wk; dst = wkb; off = b - 14336; }
  else { src = Wv; dst = wvb; off = b - 16384; }
  const long long i = off * 256 + threadIdx.x;
  const float4 v = ((const float4*)src)[i];
  ushort4 o;
  o.x = f2bf(v.x); o.y = f2bf(v.y); o.z = f2bf(v.z); o.w = f2bf(v.w);
  ((ushort4*)dst)[i] = o;
}

// ---------------- f32 [z][R][C] -> bf16 [z][C][R] ----------------
__global__ __launch_bounds__(256) void k_transpose_bf16(const float* __restrict__ src,
                                                        unsigned short* __restrict__ dst,
                                                        int R, int C) {
  __shared__ float t[32][33];
  const long long zo = (long long)blockIdx.z * R * C;
  const int c0 = blockIdx.x * 32, r0 = blockIdx.y * 32;
  const int tx = threadIdx.x & 31, ty = threadIdx.x >> 5;
#pragma unroll
  for (int i = 0; i < 4; ++i)
    t[ty + i * 8][tx] = src[zo + (long long)(r0 + ty + i * 8) * C + c0 + tx];
  __syncthreads();
#pragma unroll
  for (int i = 0; i < 4; ++i)
    dst[zo + (long long)(c0 + ty + i * 8) * R + r0 + tx] = f2bf(t[tx][ty + i * 8]);
}

// ---------------- u[h,d]=sum_e Wq[h,d,e]*bk[h,e] (sel0) / v from Wk,bq (sel1) ----------------
__global__ __launch_bounds__(256) void k_uv(const float* __restrict__ Wq, const float* __restrict__ bk,
                                            const float* __restrict__ Wk, const float* __restrict__ bq,
                                            float* __restrict__ u, float* __restrict__ v) {
  const int sel = blockIdx.y;
  const float* W = sel ? Wk : Wq;
  const float* bb = sel ? bq : bk;
  float* dst = sel ? v : u;
  const int wave = threadIdx.x >> 6, lane = threadIdx.x & 63;
  const int idx = blockIdx.x * 4 + wave;
  const int h = idx >> 9, d = idx & 511;
  const float* wr = W + ((long long)h * 512 + d) * 512 + lane * 8;
  const float* br = bb + h * 512 + lane * 8;
  float s = 0.f;
#pragma unroll
  for (int k = 0; k < 8; ++k) s += wr[k] * br[k];
#pragma unroll
  for (int off = 32; off; off >>= 1) s += __shfl_xor(s, off);
  if (lane == 0) dst[h * 512 + d] = s;
}

// ---------------- c[h] = bq[h].bk[h] ----------------
__global__ __launch_bounds__(512) void k_bdot(const float* __restrict__ bq,
                                              const float* __restrict__ bk,
                                              float* __restrict__ c) {
  const int wave = threadIdx.x >> 6, lane = threadIdx.x & 63;
  const float* a = bq + wave * 512 + lane * 8;
  const float* b = bk + wave * 512 + lane * 8;
  float s = 0.f;
#pragma unroll
  for (int k = 0; k < 8; ++k) s += a[k] * b[k];
#pragma unroll
  for (int off = 32; off; off >>= 1) s += __shfl_xor(s, off);
  if (lane == 0) c[wave] = s;
}

// ---------------- rt[b*8+h][i] = in1[b,i,:].u[h,:] + c[h]; ct from in2,v ----------------
__global__ __launch_bounds__(256) void k_rtct(const float* __restrict__ in1, const float* __restrict__ in2,
                                              const float* __restrict__ u, const float* __restrict__ v,
                                              const float* __restrict__ cbuf,
                                              float* __restrict__ rt, float* __restrict__ ct) {
  const int sel = blockIdx.y;
  const float* src = sel ? in2 : in1;
  const float* vec = sel ? v : u;
  float* dst = sel ? ct : rt;
  const int row = blockIdx.x;
  __shared__ float x[512];
  const float* p = src + (long long)row * 512;
  x[threadIdx.x] = p[threadIdx.x];
  x[threadIdx.x + 256] = p[threadIdx.x + 256];
  __syncthreads();
  const int wave = threadIdx.x >> 6, lane = threadIdx.x & 63;
  const int b = row >> 10, i = row & 1023;
#pragma unroll
  for (int t = 0; t < 2; ++t) {
    const int h = wave * 2 + t;
    const float* wv = vec + h * 512;
    float s = 0.f;
#pragma unroll
    for (int k = 0; k < 8; ++k) s += x[lane + k * 64] * wv[lane + k * 64];
#pragma unroll
    for (int off = 32; off; off >>= 1) s += __shfl_xor(s, off);
    if (lane == 0)
      dst[((long long)(b * 8 + h)) * 1024 + i] = s + (sel ? 0.f : cbuf[h]);
  }
}

// ---------------- bvo[h][e'] = sum_e bv[h][e] * Wo[h*512+e][e'] ----------------
__global__ __launch_bounds__(256) void k_bvo(const float* __restrict__ Wo,
                                             const float* __restrict__ bv,
                                             float* __restrict__ bvo) {
  const int h = blockIdx.x;
  __shared__ float bs[512];
  bs[threadIdx.x] = bv[h * 512 + threadIdx.x];
  bs[threadIdx.x + 256] = bv[h * 512 + threadIdx.x + 256];
  __syncthreads();
  float a0 = 0.f, a1 = 0.f;
  for (int e = 0; e < 512; ++e) {
    const float* row = Wo + ((long long)(h * 512 + e)) * 512;
    a0 += bs[e] * row[threadIdx.x];
    a1 += bs[e] * row[threadIdx.x + 256];
  }
  bvo[h * 512 + threadIdx.x] = a0;
  bvo[h * 512 + threadIdx.x + 256] = a1;
}

// ---- rsum[row*8+h] = sum_j Pe[row][h*1024+j]; 8192 rows, one wave per row ----
__global__ __launch_bounds__(256) void k_rsum(const unsigned short* __restrict__ P,
                                              float* __restrict__ rsum) {
  const int wid = threadIdx.x >> 6, lane = threadIdx.x & 63;
  const long long row = (long long)blockIdx.x * 4 + wid;
  const unsigned short* p = P + row * 8192;
#pragma unroll
  for (int h = 0; h < 8; ++h) {
    const b16x8 v0 = *(const b16x8*)(p + h * 1024 + lane * 16);
    const b16x8 v1 = *(const b16x8*)(p + h * 1024 + lane * 16 + 8);
    float s = 0.f;
#pragma unroll
    for (int j = 0; j < 8; ++j) s += (float)v0[j] + (float)v1[j];
#pragma unroll
    for (int off = 32; off; off >>= 1) s += __shfl_xor(s, off);
    if (lane == 0) rsum[row * 8 + h] = s;
  }
}

// ---------------- old 128x128 GEMM (small weight-product GEMMs) ----------------
template <int OM>
__global__ __launch_bounds__(256) void k_gemm_bt(
    const unsigned short* __restrict__ A, const unsigned short* __restrict__ Bt,
    void* __restrict__ Cv, const float* __restrict__ bias,
    const float* __restrict__ rAdd, const float* __restrict__ cAdd,
    int K, int lda, int ldb, int ldc,
    int azs, int azm, long long azr,
    int bzs, int bzm, long long bzr,
    int czs, long long czr, int czm, int czc,
    int biasm, int bstr, int rstr, float scale) {
  __shared__ unsigned short lA[128 * 64];
  __shared__ unsigned short lB[128 * 64];
  const int tid = threadIdx.x, wave = tid >> 6, lane = tid & 63;
  const int z = blockIdx.z;
  const int m0 = blockIdx.y * 128, n0 = blockIdx.x * 128;
  const unsigned short* Az = A + (long long)((z >> azs) & azm) * azr + (long long)m0 * lda;
  const unsigned short* Bz = Bt + (long long)((z >> bzs) & bzm) * bzr + (long long)n0 * ldb;

  const int srow = wave * 32 + (lane >> 3);
  const int scol = (lane & 7) * 8;
  const unsigned short* ga = Az + (long long)srow * lda + scol;
  const unsigned short* gb = Bz + (long long)srow * ldb + scol;
  unsigned short* laBase = &lA[(wave * 32) * 64];
  unsigned short* lbBase = &lB[(wave * 32) * 64];

  f32x4 acc[4][4] = {};
  const int wr = (wave >> 1) * 64, wc = (wave & 1) * 64;
  const int fr = lane & 15, kq = (lane >> 4) * 8;

  for (int k0 = 0; k0 < K; k0 += 64) {
#pragma unroll
    for (int i = 0; i < 4; ++i) {
      gload_lds16(ga + (long long)(i * 8) * lda + k0, laBase + (i * 8) * 64);
      gload_lds16(gb + (long long)(i * 8) * ldb + k0, lbBase + (i * 8) * 64);
    }
    __syncthreads();
#pragma unroll
    for (int kk = 0; kk < 64; kk += 32) {
      b16x8 af[4], bf[4];
#pragma unroll
      for (int i = 0; i < 4; ++i)
        af[i] = *(const b16x8*)&lA[(wr + i * 16 + fr) * 64 + kk + kq];
#pragma unroll
      for (int j = 0; j < 4; ++j)
        bf[j] = *(const b16x8*)&lB[(wc + j * 16 + fr) * 64 + kk + kq];
#pragma unroll
      for (int i = 0; i < 4; ++i)
#pragma unroll
        for (int j = 0; j < 4; ++j)
          acc[i][j] = __builtin_amdgcn_mfma_f32_16x16x32_bf16(af[i], bf[j], acc[i][j], 0, 0, 0);
    }
    __syncthreads();
  }

  const long long coff = (long long)(z >> czs) * czr + (long long)(z & czm) * czc;
  const long long zr = (long long)z * rstr;
  const int rr = (lane >> 4) * 4;
#pragma unroll
  for (int j = 0; j < 4; ++j) {
    const int col = n0 + wc + j * 16 + fr;
    const float bval = bias ? bias[(long long)(z & biasm) * bstr + col] : 0.f;
    const float ca = cAdd ? cAdd[zr + col] : 0.f;
#pragma unroll
    for (int i = 0; i < 4; ++i) {
#pragma unroll
      for (int r = 0; r < 4; ++r) {
        const int row = m0 + wr + i * 16 + rr + r;
        const float ra = rAdd ? rAdd[zr + row] : 0.f;
        const float val = (acc[i][j][r] + ra + ca) * scale + bval;
        if constexpr (OM == 1) {
          ((unsigned short*)Cv)[coff + (long long)row * ldc + col] = f2bf(val);
        } else if constexpr (OM == 2) {
          ((unsigned short*)Cv)[coff + (long long)col * ldc + row] = f2bf(val);
        } else {
          ((float*)Cv)[coff + (long long)row * ldc + col] = val;
        }
      }
    }
  }
}

// ================= 256x256 stage-early GEMM; ES=1 applies exp in epilogue ====
#define STAGE_A8(nb, koff, i)                                  \
  gload_lds16(gaL + (long long)((i) * 8) * lda + (koff) + scol, \
              &sh[nb][(wid * 32 + (i) * 8) * 64])
#define STAGE_B8(nb, koff, i)                                  \
  gload_lds16(gbL + (long long)((i) * 8) * ldb + (koff) + scol, \
              &sh[2 + (nb)][(wid * 32 + (i) * 8) * 64])

template <int OM, int ES>
__global__ __launch_bounds__(512, 2) void k_gemm8p(
    const unsigned short* __restrict__ A, const unsigned short* __restrict__ Bt,
    void* __restrict__ Cv, const float* __restrict__ bias,
    const float* __restrict__ rAdd, const float* __restrict__ cAdd,
    int K, int lda, int ldb, int ldc,
    int azs, int azm, long long azr,
    int bzs, int bzm, long long bzr,
    int czs, long long czr, int czm, int czc,
    int biasm, int bstr, int rstr, float scale, int kzm, int kzr) {
  __shared__ unsigned short sh[4][256 * 64];
  const int tid = threadIdx.x, wid = tid >> 6, lane = tid & 63;
  const int wm = wid >> 2, wn = wid & 3;

  const int gx = gridDim.x, gy = gridDim.y;
  const int nwg = gx * gy * gridDim.z;
  const int bidL = blockIdx.x + gx * (blockIdx.y + gy * blockIdx.z);
  const int q8 = nwg >> 3;
  const int idx = (bidL & 7) * q8 + (bidL >> 3);
  const int bx = idx % gx;
  const int rem = idx / gx;
  const int by = rem % gy;
  const int z = rem / gy;

  const int m0 = by * 256, n0 = bx * 256;
  const int kstart = (z & kzm) * kzr;
  const unsigned short* Az = A + (long long)((z >> azs) & azm) * azr + (long long)m0 * lda + kstart;
  const unsigned short* Bz = Bt + (long long)((z >> bzs) & bzm) * bzr + (long long)n0 * ldb + kstart;

  const int scol = (((lane & 7) ^ ((lane >> 3) & 7)) << 3);
  const unsigned short* gaL = Az + (long long)(wid * 32 + (lane >> 3)) * lda;
  const unsigned short* gbL = Bz + (long long)(wid * 32 + (lane >> 3)) * ldb;

  const int fr = lane & 15, kq = (lane >> 4) * 8;
  const int fsw = (fr & 7) << 3;
  const int rc0 = kq ^ fsw;
  const int rc1 = (32 + kq) ^ fsw;
  const int aBase = (wm * 128 + fr) * 64;
  const int bBase = (wn * 64 + fr) * 64;

  f32x4 acc[8][4] = {};
  b16x8 afr[4][2], bfr[4][2];
  const int NT = K >> 6;

#pragma unroll
  for (int i = 0; i < 4; ++i) { STAGE_A8(0, 0, i); STAGE_B8(0, 0, i); }

  for (int kt = 0; kt < NT; ++kt) {
    const int cur = kt & 1, nb = cur ^ 1;
    if (kt + 1 < NT) {
      const int ko = (kt + 1) << 6;
#pragma unroll
      for (int i = 0; i < 4; ++i) { STAGE_A8(nb, ko, i); STAGE_B8(nb, ko, i); }
      asm volatile("s_waitcnt vmcnt(8)" ::: "memory");
    } else {
      asm volatile("s_waitcnt vmcnt(0)" ::: "memory");
    }
    __builtin_amdgcn_s_barrier();
    __builtin_amdgcn_sched_barrier(0);

#pragma unroll
    for (int i = 0; i < 4; ++i) {
      afr[i][0] = *(const b16x8*)&sh[cur][aBase + i * 1024 + rc0];
      afr[i][1] = *(const b16x8*)&sh[cur][aBase + i * 1024 + rc1];
    }
#pragma unroll
    for (int j = 0; j < 2; ++j) {
      bfr[j][0] = *(const b16x8*)&sh[2 + cur][bBase + j * 1024 + rc0];
      bfr[j][1] = *(const b16x8*)&sh[2 + cur][bBase + j * 1024 + rc1];
    }
    __builtin_amdgcn_s_setprio(1);
#pragma unroll
    for (int t = 0; t < 2; ++t)
#pragma unroll
      for (int i = 0; i < 4; ++i)
#pragma unroll
        for (int j = 0; j < 2; ++j)
          acc[i][j] = __builtin_amdgcn_mfma_f32_16x16x32_bf16(afr[i][t], bfr[j][t], acc[i][j], 0, 0, 0);
    __builtin_amdgcn_s_setprio(0);
#pragma unroll
    for (int j = 2; j < 4; ++j) {
      bfr[j][0] = *(const b16x8*)&sh[2 + cur][bBase + j * 1024 + rc0];
      bfr[j][1] = *(const b16x8*)&sh[2 + cur][bBase + j * 1024 + rc1];
    }
    __builtin_amdgcn_s_setprio(1);
#pragma unroll
    for (int t = 0; t < 2; ++t)
#pragma unroll
      for (int i = 0; i < 4; ++i)
#pragma unroll
        for (int j = 2; j < 4; ++j)
          acc[i][j] = __builtin_amdgcn_mfma_f32_16x16x32_bf16(afr[i][t], bfr[j][t], acc[i][j], 0, 0, 0);
    __builtin_amdgcn_s_setprio(0);
#pragma unroll
    for (int i = 0; i < 4; ++i) {
      afr[i][0] = *(const b16x8*)&sh[cur][aBase + (i + 4) * 1024 + rc0];
      afr[i][1] = *(const b16x8*)&sh[cur][aBase + (i + 4) * 1024 + rc1];
    }
    __builtin_amdgcn_s_setprio(1);
#pragma unroll
    for (int t = 0; t < 2; ++t)
#pragma unroll
      for (int i = 0; i < 4; ++i)
#pragma unroll
        for (int j = 0; j < 2; ++j)
          acc[i + 4][j] = __builtin_amdgcn_mfma_f32_16x16x32_bf16(afr[i][t], bfr[j][t], acc[i + 4][j], 0, 0, 0);
    __builtin_amdgcn_s_setprio(0);
    __builtin_amdgcn_s_setprio(1);
#pragma unroll
    for (int t = 0; t < 2; ++t)
#pragma unroll
      for (int i = 0; i < 4; ++i)
#pragma unroll
        for (int j = 2; j < 4; ++j)
          acc[i + 4][j] = __builtin_amdgcn_mfma_f32_16x16x32_bf16(afr[i][t], bfr[j][t], acc[i + 4][j], 0, 0, 0);
    __builtin_amdgcn_s_setprio(0);

    __builtin_amdgcn_s_barrier();
  }

  const long long coff = (long long)(z >> czs) * czr + (long long)(z & czm) * czc;
  const long long zr = (long long)z * rstr;
  const int rr = (lane >> 4) * 4;
  unsigned short* flat = &sh[0][0];

#pragma unroll
  for (int j = 0; j < 4; ++j) {
    const int col = n0 + wn * 64 + j * 16 + fr;
    const float bval = bias ? bias[(long long)(z & biasm) * bstr + col] : 0.f;
    const float ca = cAdd ? cAdd[zr + col] : 0.f;
#pragma unroll
    for (int i = 0; i < 8; ++i) {
#pragma unroll
      for (int r = 0; r < 4; ++r) {
        const int row = m0 + wm * 128 + i * 16 + rr + r;
        const float ra = rAdd ? rAdd[zr + row] : 0.f;
        float val = (acc[i][j][r] + ra + ca) * scale + bval;
        if constexpr (ES) val = __expf(val);  // scores bounded: no max-sub
        const int rowL = wm * 128 + i * 16 + rr + r;
        const int colL = wn * 64 + j * 16 + fr;
        const int sR = (OM == 2) ? colL : rowL;
        const int sC = (OM == 2) ? rowL : colL;
        flat[sR * 256 + (sC ^ ((sR & 7) << 3))] = f2bf(val);
      }
    }
  }
  __builtin_amdgcn_s_barrier();
  const long long rbase = (OM == 2) ? (long long)n0 : (long long)m0;
  const long long cbase = (OM == 2) ? (long long)m0 : (long long)n0;
  unsigned short* Cb = (unsigned short*)Cv;
#pragma unroll
  for (int it = 0; it < 16; ++it) {
    const int t = it * 512 + tid;
    const int R = t >> 5;
    const int Cq = t & 31;
    const int q = Cq ^ (R & 7);
    const b16x8 v = *(const b16x8*)&flat[R * 256 + q * 8];
    *(b16x8*)(Cb + coff + (rbase + R) * ldc + cbase + Cq * 8) = v;
  }
}

// ===== 128x128 stage-early GEMM; SEG=1: per-h-segment softmax normalization ==
#define STAGE_GA(nb, koff, i)                                  \
  gload_lds16(gaL + (long long)((i) * 8) * lda + (koff) + scol, \
              &sh[nb][(wid * 32 + (i) * 8) * 64])
#define STAGE_GB(nb, koff, i)                                  \
  gload_lds16(gbL + (long long)((i) * 8) * ldb + (koff) + scol, \
              &sh[2 + (nb)][(wid * 32 + (i) * 8) * 64])

template <int OM, int SEG>
__global__ __launch_bounds__(256, 2) void k_g128(
    const unsigned short* __restrict__ A, const unsigned short* __restrict__ Bt,
    void* __restrict__ Cv, const float* __restrict__ bias,
    const float* __restrict__ rsum,
    int K, int lda, int ldb, int ldc,
    int azs, int azm, long long azr,
    int bzs, int bzm, long long bzr,
    int czs, long long czr, int czm, int czc,
    int biasm, int bstr, float scale, int kzm, int kzr) {
  __shared__ unsigned short sh[4][128 * 64];
  __shared__ float rsl[1024];
  const int tid = threadIdx.x, wid = tid >> 6, lane = tid & 63;
  const int wm = wid >> 1, wn = wid & 1;

  const int gx = gridDim.x, gy = gridDim.y;
  const int nwg = gx * gy * gridDim.z;
  const int bidL = blockIdx.x + gx * (blockIdx.y + gy * blockIdx.z);
  const int q8 = nwg >> 3;
  const int idx = (bidL & 7) * q8 + (bidL >> 3);
  const int bx = idx % gx;
  const int rem = idx / gx;
  const int by = rem % gy;
  const int z = rem / gy;

  const int m0 = by * 128, n0 = bx * 128;
  const int kstart = (z & kzm) * kzr;
  const unsigned short* Az = A + (long long)((z >> azs) & azm) * azr + (long long)m0 * lda + kstart;
  const unsigned short* Bz = Bt + (long long)((z >> bzs) & bzm) * bzr + (long long)n0 * ldb + kstart;

  const int scol = (((lane & 7) ^ ((lane >> 3) & 7)) << 3);
  const unsigned short* gaL = Az + (long long)(wid * 32 + (lane >> 3)) * lda;
  const unsigned short* gbL = Bz + (long long)(wid * 32 + (lane >> 3)) * ldb;

  const int fr = lane & 15, kq = (lane >> 4) * 8;
  const int fsw = (fr & 7) << 3;
  const int rc0 = kq ^ fsw;
  const int rc1 = (32 + kq) ^ fsw;
  const int aBase = (wm * 64 + fr) * 64;
  const int bBase = (wn * 64 + fr) * 64;
  const int rr = (lane >> 4) * 4;

  if constexpr (SEG) {
#pragma unroll
    for (int qq = 0; qq < 4; ++qq) {
      const int tt = tid * 4 + qq;
      const int row = tt >> 3, hh = tt & 7;
      rsl[tt] = 1.0f / rsum[((long long)z * 1024 + m0 + row) * 8 + hh];
    }
  }

  f32x4 acc[4][4] = {};
  f32x4 accH[4][4] = {};
  b16x8 afr[4][2], bfr[4][2];
  const int NT = K >> 6;

#pragma unroll
  for (int i = 0; i < 4; ++i) { STAGE_GA(0, 0, i); STAGE_GB(0, 0, i); }

  for (int kt = 0; kt < NT; ++kt) {
    const int cur = kt & 1, nb = cur ^ 1;
    if (kt + 1 < NT) {
      const int ko = (kt + 1) << 6;
#pragma unroll
      for (int i = 0; i < 4; ++i) { STAGE_GA(nb, ko, i); STAGE_GB(nb, ko, i); }
      asm volatile("s_waitcnt vmcnt(8)" ::: "memory");
    } else {
      asm volatile("s_waitcnt vmcnt(0)" ::: "memory");
    }
    __builtin_amdgcn_s_barrier();
    __builtin_amdgcn_sched_barrier(0);

#pragma unroll
    for (int i = 0; i < 4; ++i) {
      afr[i][0] = *(const b16x8*)&sh[cur][aBase + i * 1024 + rc0];
      afr[i][1] = *(const b16x8*)&sh[cur][aBase + i * 1024 + rc1];
    }
#pragma unroll
    for (int j = 0; j < 4; ++j) {
      bfr[j][0] = *(const b16x8*)&sh[2 + cur][bBase + j * 1024 + rc0];
      bfr[j][1] = *(const b16x8*)&sh[2 + cur][bBase + j * 1024 + rc1];
    }
#pragma unroll
    for (int t = 0; t < 2; ++t)
#pragma unroll
      for (int i = 0; i < 4; ++i)
#pragma unroll
        for (int j = 0; j < 4; ++j) {
          if constexpr (SEG)
            accH[i][j] = __builtin_amdgcn_mfma_f32_16x16x32_bf16(afr[i][t], bfr[j][t], accH[i][j], 0, 0, 0);
          else
            acc[i][j] = __builtin_amdgcn_mfma_f32_16x16x32_bf16(afr[i][t], bfr[j][t], acc[i][j], 0, 0, 0);
        }

    if constexpr (SEG) {
      if ((kt & 15) == 15) {  // h-segment boundary: acc += accH * rsinv[row][h]
        const int hh = kt >> 4;
#pragma unroll
        for (int i = 0; i < 4; ++i) {
          float sv[4];
#pragma unroll
          for (int r = 0; r < 4; ++r)
            sv[r] = rsl[(wm * 64 + i * 16 + rr + r) * 8 + hh];
#pragma unroll
          for (int j = 0; j < 4; ++j)
#pragma unroll
            for (int r = 0; r < 4; ++r) {
              acc[i][j][r] += accH[i][j][r] * sv[r];
              accH[i][j][r] = 0.f;
            }
        }
      }
    }

    __builtin_amdgcn_s_barrier();
  }

  const long long coff = (long long)(z >> czs) * czr + (long long)(z & czm) * czc;
  unsigned short* flat = &sh[0][0];

  if constexpr (OM == 1 || OM == 2) {
#pragma unroll
    for (int j = 0; j < 4; ++j) {
      const int col = n0 + wn * 64 + j * 16 + fr;
      const float bval = bias ? bias[(long long)(z & biasm) * bstr + col] : 0.f;
#pragma unroll
      for (int i = 0; i < 4; ++i) {
#pragma unroll
        for (int r = 0; r < 4; ++r) {
          const float val = acc[i][j][r] * scale + bval;
          const int rowL = wm * 64 + i * 16 + rr + r;
          const int colL = wn * 64 + j * 16 + fr;
          const int sR = (OM == 2) ? colL : rowL;
          const int sC = (OM == 2) ? rowL : colL;
          flat[sR * 128 + (sC ^ ((sR & 7) << 3))] = f2bf(val);
        }
      }
    }
    __builtin_amdgcn_s_barrier();
    const long long rbase = (OM == 2) ? (long long)n0 : (long long)m0;
    const long long cbase = (OM == 2) ? (long long)m0 : (long long)n0;
    unsigned short* Cb = (unsigned short*)Cv;
#pragma unroll
    for (int it = 0; it < 8; ++it) {
      const int t = it * 256 + tid;
      const int R = t >> 4;
      const int Cq = t & 15;
      const int q = Cq ^ (R & 7);
      const b16x8 v = *(const b16x8*)&flat[R * 128 + q * 8];
      *(b16x8*)(Cb + coff + (rbase + R) * ldc + cbase + Cq * 8) = v;
    }
  } else {
    float* fflat = (float*)flat;
    float* Cf = (float*)Cv;
#pragma unroll
    for (int j = 0; j < 4; ++j) {
      const int col = n0 + wn * 64 + j * 16 + fr;
      const float bval = bias ? bias[(long long)(z & biasm) * bstr + col] : 0.f;
#pragma unroll
      for (int i = 0; i < 4; ++i) {
#pragma unroll
        for (int r = 0; r < 4; ++r) {
          const float val = acc[i][j][r] * scale + bval;
          const int Rl = wm * 64 + i * 16 + rr + r;
          const int Cl = wn * 64 + j * 16 + fr;
          fflat[Rl * 128 + (Cl ^ ((Rl & 7) << 2))] = val;
        }
      }
    }
    __builtin_amdgcn_s_barrier();
#pragma unroll
    for (int it = 0; it < 16; ++it) {
      const int t = it * 256 + tid;
      const int R = t >> 5;
      const int Cq = t & 31;
      const int q = Cq ^ (R & 7);
      const float4 v = *(const float4*)&fflat[R * 128 + q * 4];
      *(float4*)(Cf + coff + (long long)(m0 + R) * ldc + n0 + Cq * 4) = v;
    }
  }
}

extern "C" void kernel_launch(void* const* d_in, const int* in_sizes, int n_in,
                              void* d_out, int out_size, void* d_ws, size_t ws_size,
                              hipStream_t stream) {
  const float* in1 = (const float*)d_in[0];
  const float* in2 = (const float*)d_in[1];
  const float* in3 = (const float*)d_in[2];
  const float* Wq = (const float*)d_in[3];
  const float* bq = (const float*)d_in[4];
  const float* Wk = (const float*)d_in[5];
  const float* bk = (const float*)d_in[6];
  const float* Wv = (const float*)d_in[7];
  const float* bv = (const float*)d_in[8];
  const float* Wo = (const float*)d_in[9];
  const float* bo = (const float*)d_in[10];

  const long long MB = 1024 * 1024;
  typedef unsigned short us;
  unsigned char* w = (unsigned char*)d_ws;
  us* in2b = (us*)(w);                  // 8 MB
  us* Tbuf = (us*)(w + 8 * MB);         // 64 MB: T, then Ubuf (T dead after scores)
  us* Ubuf = (us*)(w + 8 * MB);
  us* Pcat = (us*)(w + 72 * MB);        // 128 MB: P_cat = exp(scores), unnormalized
  us* in1b = (us*)(w + 200 * MB);       // 8 MB; first 256 KB become rsum after T
  float* rsum = (float*)(w + 200 * MB); // [8192 rows][8 h] f32, 256 KB
  us* in3b = (us*)(w + 208 * MB);       // 8 MB
  us* wqb = (us*)(w + 216 * MB);        // 4 MB; Wvot overwrites after Gt
  us* Wvot = (us*)(w + 216 * MB);
  us* wkb = (us*)(w + 220 * MB);        // 4 MB
  us* wvb = (us*)(w + 224 * MB);        // 4 MB
  us* wotb = (us*)(w + 228 * MB);       // 4 MB
  us* Gt = (us*)(w + 232 * MB);         // 4 MB
  float* rt = (float*)(w + 236 * MB);   // 256 KB
  float* ct = (float*)(w + 236 * MB + (256 << 10));
  float* ubuf = (float*)(w + 237 * MB);
  float* vbuf = (float*)(w + 237 * MB + (16 << 10));
  float* cbuf = (float*)(w + 237 * MB + (32 << 10));
  float* bvo = (float*)(w + 237 * MB + (48 << 10));
  if ((long long)ws_size < 238 * MB) return;

  const float iscale = 0.04419417382415922f;  // 1/sqrt(512)
  const long long SD = 1024 * 512;            // 524288

  // conversions (6 tensors, 1 launch) + Wo transpose
  k_convall<<<18432, 256, 0, stream>>>(in1, in2, in3, Wq, Wk, Wv,
                                       in1b, in2b, in3b, wqb, wkb, wvb);
  k_transpose_bf16<<<dim3(16, 128, 1), 256, 0, stream>>>(Wo, wotb, 4096, 512);

  // bias cross-terms for scores
  k_uv<<<dim3(1024, 2), 256, 0, stream>>>(Wq, bk, Wk, bq, ubuf, vbuf);
  k_bdot<<<1, 512, 0, stream>>>(bq, bk, cbuf);
  k_rtct<<<dim3(8192, 2), 256, 0, stream>>>(in1, in2, ubuf, vbuf, cbuf, rt, ct);

  // Gt[h] = Wk[h] Wq[h]^T
  k_gemm_bt<1><<<dim3(4, 4, 8), 256, 0, stream>>>(
      wkb, wqb, Gt, nullptr, nullptr, nullptr, 512, 512, 512, 512,
      0, 7, 262144LL, 0, 7, 262144LL, 0, 262144LL, 0, 0, 0, 0, 0, 1.f);

  // Wvot[h][e'][d] = (Wv_h Wo_h)^T  (overwrites wqb; Gt already done)
  k_gemm_bt<1><<<dim3(4, 4, 8), 256, 0, stream>>>(
      wotb, wvb, Wvot, nullptr, nullptr, nullptr, 512, 4096, 512, 512,
      0, 7, 512LL, 0, 7, 262144LL, 0, 262144LL, 0, 0, 0, 0, 0, 1.f);
  // bvo[h] = bv[h] @ Wo_h
  k_bvo<<<8, 256, 0, stream>>>(Wo, bv, bvo);

  // T[z=b*8+h] = X1[b] G[h]   [64][1024][512] bf16
  k_gemm8p<1, 0><<<dim3(2, 4, 64), 512, 0, stream>>>(
      in1b, Gt, Tbuf, nullptr, nullptr, nullptr, 512, 512, 512, 512,
      3, 7, SD, 0, 7, 262144LL, 0, SD, 0, 0, 0, 0, 0, 1.f, 0, 0);

  // scores -> P_cat = exp((T X2^T + rt + ct)*iscale) bf16 (unnormalized)
  k_gemm8p<1, 1><<<dim3(4, 4, 64), 512, 0, stream>>>(
      Tbuf, in2b, Pcat, nullptr, rt, ct, 512, 512, 512, 8192,
      0, 63, SD, 3, 7, SD, 3, 8388608LL, 7, 1024, 0, 0, 1024, iscale, 0, 0);

  // rsum[row][h] = segment sums of Pe; 8192 rows, 4 rows/block -> 2048 blocks
  k_rsum<<<2048, 256, 0, stream>>>(Pcat, rsum);

  // U_cat[b][e'][h*1024+s] = X3[b] Wvo_h + bvo_h  (overwrites Tbuf; T dead)
  k_gemm8p<2, 0><<<dim3(2, 4, 64), 512, 0, stream>>>(
      in3b, Wvot, Ubuf, bvo, nullptr, nullptr, 512, 512, 512, 8192,
      3, 7, SD, 0, 7, 262144LL, 3, 4194304LL, 7, 1024, 7, 512, 0, 1.f, 0, 0);

  // out[b*1024+i][e'] = sum_h (Pe_h @ U_h^T)/rsum[row,h] + bo
  // M=8192,N=512,K=8192 (128 K-tiles, 8 h-segments), 256 blocks = 1/CU
  k_g128<0, 1><<<dim3(4, 8, 8), 256, 0, stream>>>(
      Pcat, Ubuf, d_out, bo, rsum, 8192, 8192, 8192, 512,
      0, 7, 8388608LL, 0, 7, 4194304LL, 0, 524288LL, 0, 0, 0, 0, 1.f, 0, 0);
}

// Round 17
// 449.545 us; speedup vs baseline: 1.2476x; 1.0783x over previous
//
#include <hip/hip_runtime.h>
#include <hip/hip_bf16.h>

#define DEV static __device__ __forceinline__

typedef float f32x4 __attribute__((ext_vector_type(4)));
typedef __bf16 b16x8 __attribute__((ext_vector_type(8)));

DEV unsigned short f2bf(float f) {
  union { __hip_bfloat16 h; unsigned short u; } cv;
  cv.h = __float2bfloat16(f);
  return cv.u;
}

DEV void gload_lds16(const unsigned short* g, unsigned short* l) {
  __builtin_amdgcn_global_load_lds(
      (__attribute__((address_space(1))) void*)g,
      (__attribute__((address_space(3))) void*)l, 16, 0, 0);
}

// ---------------- all f32->bf16 conversions in ONE launch (6 tensors) --------
__global__ __launch_bounds__(256) void k_convall(
    const float* __restrict__ in1, const float* __restrict__ in2,
    const float* __restrict__ in3, const float* __restrict__ Wq,
    const float* __restrict__ Wk, const float* __restrict__ Wv,
    unsigned short* __restrict__ in1b, unsigned short* __restrict__ in2b,
    unsigned short* __restrict__ in3b, unsigned short* __restrict__ wqb,
    unsigned short* __restrict__ wkb, unsigned short* __restrict__ wvb) {
  const int b = blockIdx.x;
  const float* src;
  unsigned short* dst;
  long long off;
  if (b < 4096) { src = in1; dst = in1b; off = b; }
  else if (b < 8192) { src = in2; dst = in2b; off = b - 4096; }
  else if (b < 12288) { src = in3; dst = in3b; off = b - 8192; }
  else if (b < 14336) { src = Wq; dst = wqb; off = b - 12288; }
  else if (b < 16384) { src = Wk; dst = wkb; off = b - 14336; }
  else { src = Wv; dst = wvb; off = b - 16384; }
  const long long i = off * 256 + threadIdx.x;
  const float4 v = ((const float4*)src)[i];
  ushort4 o;
  o.x = f2bf(v.x); o.y = f2bf(v.y); o.z = f2bf(v.z); o.w = f2bf(v.w);
  ((ushort4*)dst)[i] = o;
}

// ---------------- f32 [z][R][C] -> bf16 [z][C][R] ----------------
__global__ __launch_bounds__(256) void k_transpose_bf16(const float* __restrict__ src,
                                                        unsigned short* __restrict__ dst,
                                                        int R, int C) {
  __shared__ float t[32][33];
  const long long zo = (long long)blockIdx.z * R * C;
  const int c0 = blockIdx.x * 32, r0 = blockIdx.y * 32;
  const int tx = threadIdx.x & 31, ty = threadIdx.x >> 5;
#pragma unroll
  for (int i = 0; i < 4; ++i)
    t[ty + i * 8][tx] = src[zo + (long long)(r0 + ty + i * 8) * C + c0 + tx];
  __syncthreads();
#pragma unroll
  for (int i = 0; i < 4; ++i)
    dst[zo + (long long)(c0 + ty + i * 8) * R + r0 + tx] = f2bf(t[tx][ty + i * 8]);
}

// ---------------- u[h,d]=sum_e Wq[h,d,e]*bk[h,e] (sel0) / v from Wk,bq (sel1) ----------------
__global__ __launch_bounds__(256) void k_uv(const float* __restrict__ Wq, const float* __restrict__ bk,
                                            const float* __restrict__ Wk, const float* __restrict__ bq,
                                            float* __restrict__ u, float* __restrict__ v) {
  const int sel = blockIdx.y;
  const float* W = sel ? Wk : Wq;
  const float* bb = sel ? bq : bk;
  float* dst = sel ? v : u;
  const int wave = threadIdx.x >> 6, lane = threadIdx.x & 63;
  const int idx = blockIdx.x * 4 + wave;
  const int h = idx >> 9, d = idx & 511;
  const float* wr = W + ((long long)h * 512 + d) * 512 + lane * 8;
  const float* br = bb + h * 512 + lane * 8;
  float s = 0.f;
#pragma unroll
  for (int k = 0; k < 8; ++k) s += wr[k] * br[k];
#pragma unroll
  for (int off = 32; off; off >>= 1) s += __shfl_xor(s, off);
  if (lane == 0) dst[h * 512 + d] = s;
}

// ---------------- c[h] = bq[h].bk[h] ----------------
__global__ __launch_bounds__(512) void k_bdot(const float* __restrict__ bq,
                                              const float* __restrict__ bk,
                                              float* __restrict__ c) {
  const int wave = threadIdx.x >> 6, lane = threadIdx.x & 63;
  const float* a = bq + wave * 512 + lane * 8;
  const float* b = bk + wave * 512 + lane * 8;
  float s = 0.f;
#pragma unroll
  for (int k = 0; k < 8; ++k) s += a[k] * b[k];
#pragma unroll
  for (int off = 32; off; off >>= 1) s += __shfl_xor(s, off);
  if (lane == 0) c[wave] = s;
}

// ---------------- rt[b*8+h][i] = in1[b,i,:].u[h,:] + c[h]; ct from in2,v ----------------
__global__ __launch_bounds__(256) void k_rtct(const float* __restrict__ in1, const float* __restrict__ in2,
                                              const float* __restrict__ u, const float* __restrict__ v,
                                              const float* __restrict__ cbuf,
                                              float* __restrict__ rt, float* __restrict__ ct) {
  const int sel = blockIdx.y;
  const float* src = sel ? in2 : in1;
  const float* vec = sel ? v : u;
  float* dst = sel ? ct : rt;
  const int row = blockIdx.x;
  __shared__ float x[512];
  const float* p = src + (long long)row * 512;
  x[threadIdx.x] = p[threadIdx.x];
  x[threadIdx.x + 256] = p[threadIdx.x + 256];
  __syncthreads();
  const int wave = threadIdx.x >> 6, lane = threadIdx.x & 63;
  const int b = row >> 10, i = row & 1023;
#pragma unroll
  for (int t = 0; t < 2; ++t) {
    const int h = wave * 2 + t;
    const float* wv = vec + h * 512;
    float s = 0.f;
#pragma unroll
    for (int k = 0; k < 8; ++k) s += x[lane + k * 64] * wv[lane + k * 64];
#pragma unroll
    for (int off = 32; off; off >>= 1) s += __shfl_xor(s, off);
    if (lane == 0)
      dst[((long long)(b * 8 + h)) * 1024 + i] = s + (sel ? 0.f : cbuf[h]);
  }
}

// ---------------- bvo[h][e'] = sum_e bv[h][e] * Wo[h*512+e][e'] ----------------
__global__ __launch_bounds__(256) void k_bvo(const float* __restrict__ Wo,
                                             const float* __restrict__ bv,
                                             float* __restrict__ bvo) {
  const int h = blockIdx.x;
  __shared__ float bs[512];
  bs[threadIdx.x] = bv[h * 512 + threadIdx.x];
  bs[threadIdx.x + 256] = bv[h * 512 + threadIdx.x + 256];
  __syncthreads();
  float a0 = 0.f, a1 = 0.f;
  for (int e = 0; e < 512; ++e) {
    const float* row = Wo + ((long long)(h * 512 + e)) * 512;
    a0 += bs[e] * row[threadIdx.x];
    a1 += bs[e] * row[threadIdx.x + 256];
  }
  bvo[h * 512 + threadIdx.x] = a0;
  bvo[h * 512 + threadIdx.x + 256] = a1;
}

// ---------------- in-place row softmax over 1024 bf16, one wave per row ----------------
__global__ __launch_bounds__(256) void k_softmax_bf16(unsigned short* __restrict__ P) {
  const int wave = threadIdx.x >> 6, lane = threadIdx.x & 63;
  unsigned short* p = P + ((long long)blockIdx.x * 4 + wave) * 1024 + lane * 16;
  const b16x8 v0 = *(const b16x8*)p;
  const b16x8 v1 = *(const b16x8*)(p + 8);
  float f[16];
#pragma unroll
  for (int j = 0; j < 8; ++j) { f[j] = (float)v0[j]; f[8 + j] = (float)v1[j]; }
  float mx = f[0];
#pragma unroll
  for (int j = 1; j < 16; ++j) mx = fmaxf(mx, f[j]);
#pragma unroll
  for (int off = 32; off; off >>= 1) mx = fmaxf(mx, __shfl_xor(mx, off));
  float sum = 0.f;
#pragma unroll
  for (int j = 0; j < 16; ++j) { f[j] = __expf(f[j] - mx); sum += f[j]; }
#pragma unroll
  for (int off = 32; off; off >>= 1) sum += __shfl_xor(sum, off);
  const float inv = 1.f / sum;
  b16x8 o0, o1;
#pragma unroll
  for (int j = 0; j < 8; ++j) { o0[j] = (__bf16)(f[j] * inv); o1[j] = (__bf16)(f[8 + j] * inv); }
  *(b16x8*)p = o0;
  *(b16x8*)(p + 8) = o1;
}

// ---------------- old 128x128 GEMM (small weight-product GEMMs) ----------------
template <int OM>
__global__ __launch_bounds__(256) void k_gemm_bt(
    const unsigned short* __restrict__ A, const unsigned short* __restrict__ Bt,
    void* __restrict__ Cv, const float* __restrict__ bias,
    const float* __restrict__ rAdd, const float* __restrict__ cAdd,
    int K, int lda, int ldb, int ldc,
    int azs, int azm, long long azr,
    int bzs, int bzm, long long bzr,
    int czs, long long czr, int czm, int czc,
    int biasm, int bstr, int rstr, float scale) {
  __shared__ unsigned short lA[128 * 64];
  __shared__ unsigned short lB[128 * 64];
  const int tid = threadIdx.x, wave = tid >> 6, lane = tid & 63;
  const int z = blockIdx.z;
  const int m0 = blockIdx.y * 128, n0 = blockIdx.x * 128;
  const unsigned short* Az = A + (long long)((z >> azs) & azm) * azr + (long long)m0 * lda;
  const unsigned short* Bz = Bt + (long long)((z >> bzs) & bzm) * bzr + (long long)n0 * ldb;

  const int srow = wave * 32 + (lane >> 3);
  const int scol = (lane & 7) * 8;
  const unsigned short* ga = Az + (long long)srow * lda + scol;
  const unsigned short* gb = Bz + (long long)srow * ldb + scol;
  unsigned short* laBase = &lA[(wave * 32) * 64];
  unsigned short* lbBase = &lB[(wave * 32) * 64];

  f32x4 acc[4][4] = {};
  const int wr = (wave >> 1) * 64, wc = (wave & 1) * 64;
  const int fr = lane & 15, kq = (lane >> 4) * 8;

  for (int k0 = 0; k0 < K; k0 += 64) {
#pragma unroll
    for (int i = 0; i < 4; ++i) {
      gload_lds16(ga + (long long)(i * 8) * lda + k0, laBase + (i * 8) * 64);
      gload_lds16(gb + (long long)(i * 8) * ldb + k0, lbBase + (i * 8) * 64);
    }
    __syncthreads();
#pragma unroll
    for (int kk = 0; kk < 64; kk += 32) {
      b16x8 af[4], bf[4];
#pragma unroll
      for (int i = 0; i < 4; ++i)
        af[i] = *(const b16x8*)&lA[(wr + i * 16 + fr) * 64 + kk + kq];
#pragma unroll
      for (int j = 0; j < 4; ++j)
        bf[j] = *(const b16x8*)&lB[(wc + j * 16 + fr) * 64 + kk + kq];
#pragma unroll
      for (int i = 0; i < 4; ++i)
#pragma unroll
        for (int j = 0; j < 4; ++j)
          acc[i][j] = __builtin_amdgcn_mfma_f32_16x16x32_bf16(af[i], bf[j], acc[i][j], 0, 0, 0);
    }
    __syncthreads();
  }

  const long long coff = (long long)(z >> czs) * czr + (long long)(z & czm) * czc;
  const long long zr = (long long)z * rstr;
  const int rr = (lane >> 4) * 4;
#pragma unroll
  for (int j = 0; j < 4; ++j) {
    const int col = n0 + wc + j * 16 + fr;
    const float bval = bias ? bias[(long long)(z & biasm) * bstr + col] : 0.f;
    const float ca = cAdd ? cAdd[zr + col] : 0.f;
#pragma unroll
    for (int i = 0; i < 4; ++i) {
#pragma unroll
      for (int r = 0; r < 4; ++r) {
        const int row = m0 + wr + i * 16 + rr + r;
        const float ra = rAdd ? rAdd[zr + row] : 0.f;
        const float val = (acc[i][j][r] + ra + ca) * scale + bval;
        if constexpr (OM == 1) {
          ((unsigned short*)Cv)[coff + (long long)row * ldc + col] = f2bf(val);
        } else if constexpr (OM == 2) {
          ((unsigned short*)Cv)[coff + (long long)col * ldc + row] = f2bf(val);
        } else {
          ((float*)Cv)[coff + (long long)row * ldc + col] = val;
        }
      }
    }
  }
}

// ================= 256x256 stage-early GEMM, LDS-coalesced epilogue (R6) ====
#define STAGE_A8(nb, koff, i)                                  \
  gload_lds16(gaL + (long long)((i) * 8) * lda + (koff) + scol, \
              &sh[nb][(wid * 32 + (i) * 8) * 64])
#define STAGE_B8(nb, koff, i)                                  \
  gload_lds16(gbL + (long long)((i) * 8) * ldb + (koff) + scol, \
              &sh[2 + (nb)][(wid * 32 + (i) * 8) * 64])

template <int OM>
__global__ __launch_bounds__(512, 2) void k_gemm8p(
    const unsigned short* __restrict__ A, const unsigned short* __restrict__ Bt,
    void* __restrict__ Cv, const float* __restrict__ bias,
    const float* __restrict__ rAdd, const float* __restrict__ cAdd,
    int K, int lda, int ldb, int ldc,
    int azs, int azm, long long azr,
    int bzs, int bzm, long long bzr,
    int czs, long long czr, int czm, int czc,
    int biasm, int bstr, int rstr, float scale, int kzm, int kzr) {
  __shared__ unsigned short sh[4][256 * 64];
  const int tid = threadIdx.x, wid = tid >> 6, lane = tid & 63;
  const int wm = wid >> 2, wn = wid & 3;

  const int gx = gridDim.x, gy = gridDim.y;
  const int nwg = gx * gy * gridDim.z;
  const int bidL = blockIdx.x + gx * (blockIdx.y + gy * blockIdx.z);
  const int q8 = nwg >> 3;
  const int idx = (bidL & 7) * q8 + (bidL >> 3);
  const int bx = idx % gx;
  const int rem = idx / gx;
  const int by = rem % gy;
  const int z = rem / gy;

  const int m0 = by * 256, n0 = bx * 256;
  const int kstart = (z & kzm) * kzr;
  const unsigned short* Az = A + (long long)((z >> azs) & azm) * azr + (long long)m0 * lda + kstart;
  const unsigned short* Bz = Bt + (long long)((z >> bzs) & bzm) * bzr + (long long)n0 * ldb + kstart;

  const int scol = (((lane & 7) ^ ((lane >> 3) & 7)) << 3);
  const unsigned short* gaL = Az + (long long)(wid * 32 + (lane >> 3)) * lda;
  const unsigned short* gbL = Bz + (long long)(wid * 32 + (lane >> 3)) * ldb;

  const int fr = lane & 15, kq = (lane >> 4) * 8;
  const int fsw = (fr & 7) << 3;
  const int rc0 = kq ^ fsw;
  const int rc1 = (32 + kq) ^ fsw;
  const int aBase = (wm * 128 + fr) * 64;
  const int bBase = (wn * 64 + fr) * 64;

  f32x4 acc[8][4] = {};
  b16x8 afr[4][2], bfr[4][2];
  const int NT = K >> 6;

#pragma unroll
  for (int i = 0; i < 4; ++i) { STAGE_A8(0, 0, i); STAGE_B8(0, 0, i); }

  for (int kt = 0; kt < NT; ++kt) {
    const int cur = kt & 1, nb = cur ^ 1;
    if (kt + 1 < NT) {
      const int ko = (kt + 1) << 6;
#pragma unroll
      for (int i = 0; i < 4; ++i) { STAGE_A8(nb, ko, i); STAGE_B8(nb, ko, i); }
      asm volatile("s_waitcnt vmcnt(8)" ::: "memory");
    } else {
      asm volatile("s_waitcnt vmcnt(0)" ::: "memory");
    }
    __builtin_amdgcn_s_barrier();
    __builtin_amdgcn_sched_barrier(0);

#pragma unroll
    for (int i = 0; i < 4; ++i) {
      afr[i][0] = *(const b16x8*)&sh[cur][aBase + i * 1024 + rc0];
      afr[i][1] = *(const b16x8*)&sh[cur][aBase + i * 1024 + rc1];
    }
#pragma unroll
    for (int j = 0; j < 2; ++j) {
      bfr[j][0] = *(const b16x8*)&sh[2 + cur][bBase + j * 1024 + rc0];
      bfr[j][1] = *(const b16x8*)&sh[2 + cur][bBase + j * 1024 + rc1];
    }
    __builtin_amdgcn_s_setprio(1);
#pragma unroll
    for (int t = 0; t < 2; ++t)
#pragma unroll
      for (int i = 0; i < 4; ++i)
#pragma unroll
        for (int j = 0; j < 2; ++j)
          acc[i][j] = __builtin_amdgcn_mfma_f32_16x16x32_bf16(afr[i][t], bfr[j][t], acc[i][j], 0, 0, 0);
    __builtin_amdgcn_s_setprio(0);
#pragma unroll
    for (int j = 2; j < 4; ++j) {
      bfr[j][0] = *(const b16x8*)&sh[2 + cur][bBase + j * 1024 + rc0];
      bfr[j][1] = *(const b16x8*)&sh[2 + cur][bBase + j * 1024 + rc1];
    }
    __builtin_amdgcn_s_setprio(1);
#pragma unroll
    for (int t = 0; t < 2; ++t)
#pragma unroll
      for (int i = 0; i < 4; ++i)
#pragma unroll
        for (int j = 2; j < 4; ++j)
          acc[i][j] = __builtin_amdgcn_mfma_f32_16x16x32_bf16(afr[i][t], bfr[j][t], acc[i][j], 0, 0, 0);
    __builtin_amdgcn_s_setprio(0);
#pragma unroll
    for (int i = 0; i < 4; ++i) {
      afr[i][0] = *(const b16x8*)&sh[cur][aBase + (i + 4) * 1024 + rc0];
      afr[i][1] = *(const b16x8*)&sh[cur][aBase + (i + 4) * 1024 + rc1];
    }
    __builtin_amdgcn_s_setprio(1);
#pragma unroll
    for (int t = 0; t < 2; ++t)
#pragma unroll
      for (int i = 0; i < 4; ++i)
#pragma unroll
        for (int j = 0; j < 2; ++j)
          acc[i + 4][j] = __builtin_amdgcn_mfma_f32_16x16x32_bf16(afr[i][t], bfr[j][t], acc[i + 4][j], 0, 0, 0);
    __builtin_amdgcn_s_setprio(0);
    __builtin_amdgcn_s_setprio(1);
#pragma unroll
    for (int t = 0; t < 2; ++t)
#pragma unroll
      for (int i = 0; i < 4; ++i)
#pragma unroll
        for (int j = 2; j < 4; ++j)
          acc[i + 4][j] = __builtin_amdgcn_mfma_f32_16x16x32_bf16(afr[i][t], bfr[j][t], acc[i + 4][j], 0, 0, 0);
    __builtin_amdgcn_s_setprio(0);

    __builtin_amdgcn_s_barrier();
  }

  const long long coff = (long long)(z >> czs) * czr + (long long)(z & czm) * czc;
  const long long zr = (long long)z * rstr;
  const int rr = (lane >> 4) * 4;
  unsigned short* flat = &sh[0][0];

#pragma unroll
  for (int j = 0; j < 4; ++j) {
    const int col = n0 + wn * 64 + j * 16 + fr;
    const float bval = bias ? bias[(long long)(z & biasm) * bstr + col] : 0.f;
    const float ca = cAdd ? cAdd[zr + col] : 0.f;
#pragma unroll
    for (int i = 0; i < 8; ++i) {
#pragma unroll
      for (int r = 0; r < 4; ++r) {
        const int row = m0 + wm * 128 + i * 16 + rr + r;
        const float ra = rAdd ? rAdd[zr + row] : 0.f;
        const float val = (acc[i][j][r] + ra + ca) * scale + bval;
        const int rowL = wm * 128 + i * 16 + rr + r;
        const int colL = wn * 64 + j * 16 + fr;
        const int sR = (OM == 2) ? colL : rowL;
        const int sC = (OM == 2) ? rowL : colL;
        flat[sR * 256 + (sC ^ ((sR & 7) << 3))] = f2bf(val);
      }
    }
  }
  __builtin_amdgcn_s_barrier();
  const long long rbase = (OM == 2) ? (long long)n0 : (long long)m0;
  const long long cbase = (OM == 2) ? (long long)m0 : (long long)n0;
  unsigned short* Cb = (unsigned short*)Cv;
#pragma unroll
  for (int it = 0; it < 16; ++it) {
    const int t = it * 512 + tid;
    const int R = t >> 5;
    const int Cq = t & 31;
    const int q = Cq ^ (R & 7);
    const b16x8 v = *(const b16x8*)&flat[R * 256 + q * 8];
    *(b16x8*)(Cb + coff + (rbase + R) * ldc + cbase + Cq * 8) = v;
  }
}

// ================= 128x128 stage-early GEMM (deep-K GEMMs) =====
#define STAGE_GA(nb, koff, i)                                  \
  gload_lds16(gaL + (long long)((i) * 8) * lda + (koff) + scol, \
              &sh[nb][(wid * 32 + (i) * 8) * 64])
#define STAGE_GB(nb, koff, i)                                  \
  gload_lds16(gbL + (long long)((i) * 8) * ldb + (koff) + scol, \
              &sh[2 + (nb)][(wid * 32 + (i) * 8) * 64])

template <int OM>
__global__ __launch_bounds__(256, 2) void k_g128(
    const unsigned short* __restrict__ A, const unsigned short* __restrict__ Bt,
    void* __restrict__ Cv, const float* __restrict__ bias,
    const float* __restrict__ rAdd, const float* __restrict__ cAdd,
    int K, int lda, int ldb, int ldc,
    int azs, int azm, long long azr,
    int bzs, int bzm, long long bzr,
    int czs, long long czr, int czm, int czc,
    int biasm, int bstr, int rstr, float scale, int kzm, int kzr) {
  __shared__ unsigned short sh[4][128 * 64];
  const int tid = threadIdx.x, wid = tid >> 6, lane = tid & 63;
  const int wm = wid >> 1, wn = wid & 1;

  const int gx = gridDim.x, gy = gridDim.y;
  const int nwg = gx * gy * gridDim.z;
  const int bidL = blockIdx.x + gx * (blockIdx.y + gy * blockIdx.z);
  const int q8 = nwg >> 3;
  const int idx = (bidL & 7) * q8 + (bidL >> 3);
  const int bx = idx % gx;
  const int rem = idx / gx;
  const int by = rem % gy;
  const int z = rem / gy;

  const int m0 = by * 128, n0 = bx * 128;
  const int kstart = (z & kzm) * kzr;
  const unsigned short* Az = A + (long long)((z >> azs) & azm) * azr + (long long)m0 * lda + kstart;
  const unsigned short* Bz = Bt + (long long)((z >> bzs) & bzm) * bzr + (long long)n0 * ldb + kstart;

  const int scol = (((lane & 7) ^ ((lane >> 3) & 7)) << 3);
  const unsigned short* gaL = Az + (long long)(wid * 32 + (lane >> 3)) * lda;
  const unsigned short* gbL = Bz + (long long)(wid * 32 + (lane >> 3)) * ldb;

  const int fr = lane & 15, kq = (lane >> 4) * 8;
  const int fsw = (fr & 7) << 3;
  const int rc0 = kq ^ fsw;
  const int rc1 = (32 + kq) ^ fsw;
  const int aBase = (wm * 64 + fr) * 64;
  const int bBase = (wn * 64 + fr) * 64;

  f32x4 acc[4][4] = {};
  b16x8 afr[4][2], bfr[4][2];
  const int NT = K >> 6;

#pragma unroll
  for (int i = 0; i < 4; ++i) { STAGE_GA(0, 0, i); STAGE_GB(0, 0, i); }

  for (int kt = 0; kt < NT; ++kt) {
    const int cur = kt & 1, nb = cur ^ 1;
    if (kt + 1 < NT) {
      const int ko = (kt + 1) << 6;
#pragma unroll
      for (int i = 0; i < 4; ++i) { STAGE_GA(nb, ko, i); STAGE_GB(nb, ko, i); }
      asm volatile("s_waitcnt vmcnt(8)" ::: "memory");
    } else {
      asm volatile("s_waitcnt vmcnt(0)" ::: "memory");
    }
    __builtin_amdgcn_s_barrier();
    __builtin_amdgcn_sched_barrier(0);

#pragma unroll
    for (int i = 0; i < 4; ++i) {
      afr[i][0] = *(const b16x8*)&sh[cur][aBase + i * 1024 + rc0];
      afr[i][1] = *(const b16x8*)&sh[cur][aBase + i * 1024 + rc1];
    }
#pragma unroll
    for (int j = 0; j < 4; ++j) {
      bfr[j][0] = *(const b16x8*)&sh[2 + cur][bBase + j * 1024 + rc0];
      bfr[j][1] = *(const b16x8*)&sh[2 + cur][bBase + j * 1024 + rc1];
    }
#pragma unroll
    for (int t = 0; t < 2; ++t)
#pragma unroll
      for (int i = 0; i < 4; ++i)
#pragma unroll
        for (int j = 0; j < 4; ++j)
          acc[i][j] = __builtin_amdgcn_mfma_f32_16x16x32_bf16(afr[i][t], bfr[j][t], acc[i][j], 0, 0, 0);

    __builtin_amdgcn_s_barrier();
  }

  const long long coff = (long long)(z >> czs) * czr + (long long)(z & czm) * czc;
  const long long zr = (long long)z * rstr;
  const int rr = (lane >> 4) * 4;
  unsigned short* flat = &sh[0][0];

  if constexpr (OM == 1 || OM == 2) {
#pragma unroll
    for (int j = 0; j < 4; ++j) {
      const int col = n0 + wn * 64 + j * 16 + fr;
      const float bval = bias ? bias[(long long)(z & biasm) * bstr + col] : 0.f;
#pragma unroll
      for (int i = 0; i < 4; ++i) {
#pragma unroll
        for (int r = 0; r < 4; ++r) {
          const float val = acc[i][j][r] * scale + bval;
          const int rowL = wm * 64 + i * 16 + rr + r;
          const int colL = wn * 64 + j * 16 + fr;
          const int sR = (OM == 2) ? colL : rowL;
          const int sC = (OM == 2) ? rowL : colL;
          flat[sR * 128 + (sC ^ ((sR & 7) << 3))] = f2bf(val);
        }
      }
    }
    __builtin_amdgcn_s_barrier();
    const long long rbase = (OM == 2) ? (long long)n0 : (long long)m0;
    const long long cbase = (OM == 2) ? (long long)m0 : (long long)n0;
    unsigned short* Cb = (unsigned short*)Cv;
#pragma unroll
    for (int it = 0; it < 8; ++it) {
      const int t = it * 256 + tid;
      const int R = t >> 4;
      const int Cq = t & 15;
      const int q = Cq ^ (R & 7);
      const b16x8 v = *(const b16x8*)&flat[R * 128 + q * 8];
      *(b16x8*)(Cb + coff + (rbase + R) * ldc + cbase + Cq * 8) = v;
    }
  } else {
    float* fflat = (float*)flat;
    float* Cf = (float*)Cv;
#pragma unroll
    for (int j = 0; j < 4; ++j) {
      const int col = n0 + wn * 64 + j * 16 + fr;
      const float bval = bias ? bias[(long long)(z & biasm) * bstr + col] : 0.f;
#pragma unroll
      for (int i = 0; i < 4; ++i) {
#pragma unroll
        for (int r = 0; r < 4; ++r) {
          const float val = acc[i][j][r] * scale + bval;
          const int Rl = wm * 64 + i * 16 + rr + r;
          const int Cl = wn * 64 + j * 16 + fr;
          fflat[Rl * 128 + (Cl ^ ((Rl & 7) << 2))] = val;
        }
      }
    }
    __builtin_amdgcn_s_barrier();
#pragma unroll
    for (int it = 0; it < 16; ++it) {
      const int t = it * 256 + tid;
      const int R = t >> 5;
      const int Cq = t & 31;
      const int q = Cq ^ (R & 7);
      const float4 v = *(const float4*)&fflat[R * 128 + q * 4];
      *(float4*)(Cf + coff + (long long)(m0 + R) * ldc + n0 + Cq * 4) = v;
    }
  }
}

extern "C" void kernel_launch(void* const* d_in, const int* in_sizes, int n_in,
                              void* d_out, int out_size, void* d_ws, size_t ws_size,
                              hipStream_t stream) {
  const float* in1 = (const float*)d_in[0];
  const float* in2 = (const float*)d_in[1];
  const float* in3 = (const float*)d_in[2];
  const float* Wq = (const float*)d_in[3];
  const float* bq = (const float*)d_in[4];
  const float* Wk = (const float*)d_in[5];
  const float* bk = (const float*)d_in[6];
  const float* Wv = (const float*)d_in[7];
  const float* bv = (const float*)d_in[8];
  const float* Wo = (const float*)d_in[9];
  const float* bo = (const float*)d_in[10];

  const long long MB = 1024 * 1024;
  typedef unsigned short us;
  unsigned char* w = (unsigned char*)d_ws;
  us* in2b = (us*)(w);                  // 8 MB
  us* Tbuf = (us*)(w + 8 * MB);         // 64 MB: T, then Ubuf overwrites (T dead after scores)
  us* Ubuf = (us*)(w + 8 * MB);         //        U_cat [8][512][8192]
  us* Pcat = (us*)(w + 72 * MB);        // 128 MB: P_cat [8192][8192] bf16
  us* in1b = (us*)(w + 200 * MB);       // 8 MB
  us* in3b = (us*)(w + 208 * MB);       // 8 MB
  us* wqb = (us*)(w + 216 * MB);        // 4 MB (Wvot reuses after Gt)
  us* Wvot = (us*)(w + 216 * MB);
  us* wkb = (us*)(w + 220 * MB);        // 4 MB
  us* wvb = (us*)(w + 224 * MB);        // 4 MB
  us* wotb = (us*)(w + 228 * MB);       // 4 MB
  us* Gt = (us*)(w + 232 * MB);         // 4 MB
  float* rt = (float*)(w + 236 * MB);   // 256 KB
  float* ct = (float*)(w + 236 * MB + (256 << 10));
  float* ubuf = (float*)(w + 237 * MB);
  float* vbuf = (float*)(w + 237 * MB + (16 << 10));
  float* cbuf = (float*)(w + 237 * MB + (32 << 10));
  float* bvo = (float*)(w + 237 * MB + (48 << 10));
  if ((long long)ws_size < 238 * MB) return;

  const float iscale = 0.04419417382415922f;  // 1/sqrt(512)
  const long long SD = 1024 * 512;            // 524288

  // conversions (6 tensors, 1 launch) + Wo transpose
  k_convall<<<18432, 256, 0, stream>>>(in1, in2, in3, Wq, Wk, Wv,
                                       in1b, in2b, in3b, wqb, wkb, wvb);
  k_transpose_bf16<<<dim3(16, 128, 1), 256, 0, stream>>>(Wo, wotb, 4096, 512);

  // bias cross-terms for scores
  k_uv<<<dim3(1024, 2), 256, 0, stream>>>(Wq, bk, Wk, bq, ubuf, vbuf);
  k_bdot<<<1, 512, 0, stream>>>(bq, bk, cbuf);
  k_rtct<<<dim3(8192, 2), 256, 0, stream>>>(in1, in2, ubuf, vbuf, cbuf, rt, ct);

  // Gt[h] = Wk[h] Wq[h]^T  (T = X1 G with Bt=Gt)
  k_gemm_bt<1><<<dim3(4, 4, 8), 256, 0, stream>>>(
      wkb, wqb, Gt, nullptr, nullptr, nullptr, 512, 512, 512, 512,
      0, 7, 262144LL, 0, 7, 262144LL, 0, 262144LL, 0, 0, 0, 0, 0, 1.f);

  // Wvot[h][e'][d] = (Wv_h Wo_h)^T  (overwrites wqb; Gt already done)
  k_gemm_bt<1><<<dim3(4, 4, 8), 256, 0, stream>>>(
      wotb, wvb, Wvot, nullptr, nullptr, nullptr, 512, 4096, 512, 512,
      0, 7, 512LL, 0, 7, 262144LL, 0, 262144LL, 0, 0, 0, 0, 0, 1.f);
  // bvo[h] = bv[h] @ Wo_h
  k_bvo<<<8, 256, 0, stream>>>(Wo, bv, bvo);

  // T[z=b*8+h] = X1[b] G[h]   [64][1024][512] bf16
  k_gemm8p<1><<<dim3(2, 4, 64), 512, 0, stream>>>(
      in1b, Gt, Tbuf, nullptr, nullptr, nullptr, 512, 512, 512, 512,
      3, 7, SD, 0, 7, 262144LL, 0, SD, 0, 0, 0, 0, 0, 1.f, 0, 0);

  // scores -> P_cat[b*1024+i][h*1024+j] = (T X2^T + rt + ct)*iscale, all 64 z
  k_gemm8p<1><<<dim3(4, 4, 64), 512, 0, stream>>>(
      Tbuf, in2b, Pcat, nullptr, rt, ct, 512, 512, 512, 8192,
      0, 63, SD, 3, 7, SD, 3, 8388608LL, 7, 1024, 0, 0, 1024, iscale, 0, 0);

  // softmax: 65536 rows of 1024, in place
  k_softmax_bf16<<<16384, 256, 0, stream>>>(Pcat);

  // U_cat[b][e'][h*1024+s] = X3[b] Wvo_h + bvo_h  (overwrites Tbuf; T dead)
  k_gemm8p<2><<<dim3(2, 4, 64), 512, 0, stream>>>(
      in3b, Wvot, Ubuf, bvo, nullptr, nullptr, 512, 512, 512, 8192,
      3, 7, SD, 0, 7, 262144LL, 3, 4194304LL, 7, 1024, 7, 512, 0, 1.f, 0, 0);

  // out[b*1024+i][e'] = P_cat[b] @ U_cat[b]^T + bo : M=8192,N=512,K=8192,
  // 128 K-tiles, grid 256 blocks = 1/CU, f32 direct to d_out
  k_g128<0><<<dim3(4, 8, 8), 256, 0, stream>>>(
      Pcat, Ubuf, d_out, bo, nullptr, nullptr, 8192, 8192, 8192, 512,
      0, 7, 8388608LL, 0, 7, 4194304LL, 0, 524288LL, 0, 0, 0, 0, 0, 1.f, 0, 0);
}